// Round 6
// baseline (643.929 us; speedup 1.0000x reference)
//
#include <hip/hip_runtime.h>
#include <hip/hip_bf16.h>

#define RG86_NN 50000
#define RG86_NE 320000
#define RG86_NR 3
#define RG86_DIN 768
#define RG86_HID 256
#define RG86_OUT 64

typedef __bf16 rg_bv8 __attribute__((ext_vector_type(8)));
typedef short rg_sv8 __attribute__((ext_vector_type(8)));
typedef float rg_fv4 __attribute__((ext_vector_type(4)));
typedef unsigned int rg_u32;

static __device__ float rg_b2f(unsigned short u) {
  return __uint_as_float(((unsigned int)u) << 16);
}
static __device__ unsigned short rg_f2b(float f) {
  unsigned int u = __float_as_uint(f);
  u += 0x7FFFu + ((u >> 16) & 1u);
  return (unsigned short)(u >> 16);
}

// async global->LDS, 16B per lane. lds arg must be the WAVE-uniform base;
// HW scatters lane l to base + l*16.
static __device__ __forceinline__ void rg_gl16(const void* g, void* lds_wave_base) {
  __builtin_amdgcn_global_load_lds(
      (const __attribute__((address_space(1))) rg_u32*)(unsigned long long)(uintptr_t)g,
      (__attribute__((address_space(3))) rg_u32*)(unsigned int)(uintptr_t)lds_wave_base,
      16, 0, 0);
}

__global__ void RGATModel_86371792322702_kernel() {}

// fp32 [rows][cols] -> bf16 [cols][rows]
__global__ void rg_castT(const float* in, unsigned short* out, int rows, int cols) {
  int i = blockIdx.x * 256 + threadIdx.x;
  if (i < rows * cols) {
    int r = i / cols, c = i % cols;
    out[(size_t)c * rows + r] = rg_f2b(in[i]);
  }
}

// 3-relation [256][256] transpose cast (one launch for a whole conv weight)
__global__ void rg_castT3(const float* in, unsigned short* out) {
  int i = blockIdx.x * 256 + threadIdx.x;
  if (i < RG86_NR * RG86_HID * RG86_HID) {
    int r = i >> 16, j = i & 65535;
    int row = j >> 8, col = j & 255;
    out[(r << 16) + (col << 8) + row] = rg_f2b(in[i]);
  }
}

// wq[r][c] = sum_o W[r][c][o]*q[o]; wk likewise. One wave per (r,c) row.
__global__ void rg_wqk(const float* W, const float* q, const float* k,
                       float* wq, float* wk) {
  int lane = threadIdx.x & 63;
  int p = blockIdx.x * 4 + (threadIdx.x >> 6);
  if (p >= RG86_NR * RG86_HID) return;
  const float* wr = W + (size_t)p * RG86_HID;
  float qv = 0.f, kv = 0.f;
  for (int j = lane; j < RG86_HID; j += 64) {
    float w = wr[j];
    qv += w * q[j];
    kv += w * k[j];
  }
  for (int o = 32; o >= 1; o >>= 1) { qv += __shfl_xor(qv, o); kv += __shfl_xor(kv, o); }
  if (lane == 0) { wq[p] = qv; wk[p] = kv; }
}

// qd[r][n] = h[n] . wq[r]  (identity: (h@W)q == h@(Wq)). Wave per node, 6 dots.
__global__ void rg_qk2(const unsigned short* h, const float* wq, const float* wk,
                       float* qd, float* kd) {
  int lane = threadIdx.x & 63;
  int n = blockIdx.x * 4 + (threadIdx.x >> 6);
  if (n >= RG86_NN) return;
  ushort4 hv = *(const ushort4*)(h + (size_t)n * RG86_HID + lane * 4);
  float h0 = rg_b2f(hv.x), h1 = rg_b2f(hv.y), h2 = rg_b2f(hv.z), h3 = rg_b2f(hv.w);
  float acc[6];
#pragma unroll
  for (int r = 0; r < RG86_NR; r++) {
    const float* wqr = wq + r * RG86_HID + lane * 4;
    const float* wkr = wk + r * RG86_HID + lane * 4;
    acc[r] = h0 * wqr[0] + h1 * wqr[1] + h2 * wqr[2] + h3 * wqr[3];
    acc[3 + r] = h0 * wkr[0] + h1 * wkr[1] + h2 * wkr[2] + h3 * wkr[3];
  }
#pragma unroll
  for (int j = 0; j < 6; j++)
    for (int o = 32; o >= 1; o >>= 1) acc[j] += __shfl_xor(acc[j], o);
  if (lane == 0) {
#pragma unroll
    for (int r = 0; r < RG86_NR; r++) {
      qd[r * RG86_NN + n] = acc[r];
      kd[r * RG86_NN + n] = acc[3 + r];
    }
  }
}

// MFMA GEMM, 2-phase double-buffered: issue next-tile global_load_lds into
// buf^1 BEFORE computing buf; single __syncthreads per K-step (its vmcnt(0)
// drain lands after the compute phase -> stage latency hidden). bf16 in/out,
// 128x64 tile, BK=64, XOR swizzle, XCD-bijective block swizzle, mt-major.
// split: N=768 fused 3-relation output -> C + (col>>8)*NN*256, stride 256.
__global__ __launch_bounds__(256) void rg_gemm2(
    const unsigned short* A, const unsigned short* Bt, const float* bias,
    unsigned short* C, int M, int N, int K, int relu, int split) {
  __shared__ unsigned short sA[2][128 * 64];
  __shared__ unsigned short sB[2][64 * 64];
  int tid = threadIdx.x;
  int wv = tid >> 6, lane = tid & 63;
  int nwg = gridDim.x;
  int q = nwg >> 3, rres = nwg & 7;
  int xcd = blockIdx.x & 7, jj = blockIdx.x >> 3;
  int wg = (xcd < rres ? xcd * (q + 1) : rres * (q + 1) + (xcd - rres) * q) + jj;
  int ntiles = N >> 6;
  int mt = wg / ntiles, nt = wg - mt * ntiles;
  int m0 = mt * 128, n0 = nt * 64;
  int frow = lane & 15, fhi = lane >> 4;
  // staging addresses (k0-independent parts)
  int sr = tid >> 3, ss = tid & 7;          // idx = i*256+tid -> r = i*32+sr
  rg_fv4 acc[2][4] = {};

  auto stage = [&](int buf, int k0) {
#pragma unroll
    for (int i = 0; i < 4; i++) {
      int r = i * 32 + sr;
      int gr = m0 + r;
      if (gr >= M) gr = M - 1;
      const unsigned short* gp = A + (size_t)gr * K + k0 + ((ss ^ (r & 7)) << 3);
      rg_gl16(gp, (char*)sA[buf] + (size_t)(i * 256 + wv * 64) * 16);
    }
#pragma unroll
    for (int i = 0; i < 2; i++) {
      int r = i * 32 + sr;
      const unsigned short* gp = Bt + (size_t)(n0 + r) * K + k0 + ((ss ^ (r & 7)) << 3);
      rg_gl16(gp, (char*)sB[buf] + (size_t)(i * 256 + wv * 64) * 16);
    }
  };

  int nst = K >> 6;
  stage(0, 0);
  __syncthreads();
  int cur = 0;
  for (int t = 0; t < nst; t++) {
    if (t + 1 < nst) stage(cur ^ 1, (t + 1) << 6);
#pragma unroll
    for (int ks = 0; ks < 2; ks++) {
      rg_bv8 af[2], bf[4];
#pragma unroll
      for (int mf = 0; mf < 2; mf++) {
        int r = wv * 32 + mf * 16 + frow;
        int slot = (ks * 4 + fhi) ^ (r & 7);
        af[mf] = *(const rg_bv8*)((const char*)sA[cur] + r * 128 + slot * 16);
      }
#pragma unroll
      for (int nf = 0; nf < 4; nf++) {
        int r = nf * 16 + frow;
        int slot = (ks * 4 + fhi) ^ (r & 7);
        bf[nf] = *(const rg_bv8*)((const char*)sB[cur] + r * 128 + slot * 16);
      }
#pragma unroll
      for (int mf = 0; mf < 2; mf++)
#pragma unroll
        for (int nf = 0; nf < 4; nf++)
          acc[mf][nf] = __builtin_amdgcn_mfma_f32_16x16x32_bf16(af[mf], bf[nf],
                                                                acc[mf][nf], 0, 0, 0);
    }
    __syncthreads();  // drains stage vmcnt + lgkm; buf swap safe
    cur ^= 1;
  }
#pragma unroll
  for (int mf = 0; mf < 2; mf++) {
#pragma unroll
    for (int nf = 0; nf < 4; nf++) {
      int col = n0 + nf * 16 + frow;
      float bv = bias ? bias[col] : 0.f;
#pragma unroll
      for (int r = 0; r < 4; r++) {
        int row = m0 + wv * 32 + mf * 16 + fhi * 4 + r;
        if (row < M) {
          float v = acc[mf][nf][r] + bv;
          if (relu && v < 0.f) v = 0.f;
          if (split)
            C[((size_t)(col >> 8) * RG86_NN + row) * 256 + (col & 255)] = rg_f2b(v);
          else
            C[(size_t)row * N + col] = rg_f2b(v);
        }
      }
    }
  }
}

// fp32-A GEMM, 2-phase double-buffered like rg_gemm2. A staged as fp32 via
// global_load_lds (32B slots, XOR swizzle), converted bf16 at fragment load.
__global__ __launch_bounds__(256) void rg_gemm2f(
    const float* A, const unsigned short* Bt, const float* bias,
    unsigned short* C, int M, int N, int K, int relu) {
  __shared__ float sA[2][128 * 64];          // 2 x 32 KB
  __shared__ unsigned short sB[2][64 * 64];  // 2 x 8 KB
  int tid = threadIdx.x;
  int wv = tid >> 6, lane = tid & 63;
  int nwg = gridDim.x;
  int q = nwg >> 3, rres = nwg & 7;
  int xcd = blockIdx.x & 7, jj = blockIdx.x >> 3;
  int wg = (xcd < rres ? xcd * (q + 1) : rres * (q + 1) + (xcd - rres) * q) + jj;
  int ntiles = N >> 6;
  int mt = wg / ntiles, nt = wg - mt * ntiles;
  int m0 = mt * 128, n0 = nt * 64;
  int frow = lane & 15, fhi = lane >> 4;
  int sr8 = tid >> 3, ss8 = tid & 7;    // B staging
  int sr16 = tid >> 4, hs = tid & 15;   // A staging (16 lanes / 256B row)
  rg_fv4 acc[2][4] = {};

  auto stage = [&](int buf, int k0) {
#pragma unroll
    for (int i = 0; i < 2; i++) {
      int r = i * 32 + sr8;
      const unsigned short* gp = Bt + (size_t)(n0 + r) * K + k0 + ((ss8 ^ (r & 7)) << 3);
      rg_gl16(gp, (char*)sB[buf] + (size_t)(i * 256 + wv * 64) * 16);
    }
#pragma unroll
    for (int i = 0; i < 8; i++) {
      int r = i * 16 + sr16;
      int gr = m0 + r;
      if (gr >= M) gr = M - 1;
      const float* gp = A + (size_t)gr * K + k0 +
                        ((((hs >> 1) ^ (r & 7)) << 3) + ((hs & 1) << 2));
      rg_gl16(gp, (char*)sA[buf] + (size_t)(i * 256 + wv * 64) * 16);
    }
  };

  int nst = K >> 6;
  stage(0, 0);
  __syncthreads();
  int cur = 0;
  for (int t = 0; t < nst; t++) {
    if (t + 1 < nst) stage(cur ^ 1, (t + 1) << 6);
#pragma unroll
    for (int ks = 0; ks < 2; ks++) {
      rg_bv8 af[2], bf[4];
#pragma unroll
      for (int mf = 0; mf < 2; mf++) {
        int r = wv * 32 + mf * 16 + frow;
        int sp = (ks * 4 + fhi) ^ (r & 7);
        const float* ap = sA[cur] + r * 64 + sp * 8;
        float4 f0 = *(const float4*)ap;
        float4 f1 = *(const float4*)(ap + 4);
        rg_sv8 av;
        av[0] = (short)rg_f2b(f0.x); av[1] = (short)rg_f2b(f0.y);
        av[2] = (short)rg_f2b(f0.z); av[3] = (short)rg_f2b(f0.w);
        av[4] = (short)rg_f2b(f1.x); av[5] = (short)rg_f2b(f1.y);
        av[6] = (short)rg_f2b(f1.z); av[7] = (short)rg_f2b(f1.w);
        af[mf] = *(rg_bv8*)&av;
      }
#pragma unroll
      for (int nf = 0; nf < 4; nf++) {
        int r = nf * 16 + frow;
        int slot = (ks * 4 + fhi) ^ (r & 7);
        bf[nf] = *(const rg_bv8*)((const char*)sB[cur] + r * 128 + slot * 16);
      }
#pragma unroll
      for (int mf = 0; mf < 2; mf++)
#pragma unroll
        for (int nf = 0; nf < 4; nf++)
          acc[mf][nf] = __builtin_amdgcn_mfma_f32_16x16x32_bf16(af[mf], bf[nf],
                                                                acc[mf][nf], 0, 0, 0);
    }
    __syncthreads();
    cur ^= 1;
  }
#pragma unroll
  for (int mf = 0; mf < 2; mf++) {
#pragma unroll
    for (int nf = 0; nf < 4; nf++) {
      int col = n0 + nf * 16 + frow;
      float bv = bias ? bias[col] : 0.f;
#pragma unroll
      for (int r = 0; r < 4; r++) {
        int row = m0 + wv * 32 + mf * 16 + fhi * 4 + r;
        if (row < M) {
          float v = acc[mf][nf][r] + bv;
          if (relu && v < 0.f) v = 0.f;
          C[(size_t)row * N + col] = rg_f2b(v);
        }
      }
    }
  }
}

__global__ void rg_hist(const int* d, int* counts) {
  int e = blockIdx.x * 256 + threadIdx.x;
  if (e < RG86_NE) atomicAdd(&counts[d[e]], 1);
}

// ---- multi-block exclusive scan of counts[n] -> rowptr/cursor ----
__global__ void rg_scan1(const int* counts, int* tmp, int* bsum, int n) {
  int b = blockIdx.x, t = threadIdx.x;
  int base = b * 1024 + t * 4;
  int v0 = 0, v1 = 0, v2 = 0, v3 = 0;
  if (base + 3 < n) {
    int4 v = *(const int4*)(counts + base);
    v0 = v.x; v1 = v.y; v2 = v.z; v3 = v.w;
  } else {
    if (base + 0 < n) v0 = counts[base + 0];
    if (base + 1 < n) v1 = counts[base + 1];
    if (base + 2 < n) v2 = counts[base + 2];
    if (base + 3 < n) v3 = counts[base + 3];
  }
  int tsum = v0 + v1 + v2 + v3;
  int lane = t & 63, wave = t >> 6;
  int s = tsum;
  for (int off = 1; off < 64; off <<= 1) {
    int u = __shfl_up(s, off);
    if (lane >= off) s += u;
  }
  __shared__ int wsum[4];
  if (lane == 63) wsum[wave] = s;
  __syncthreads();
  int woff = 0;
  for (int w = 0; w < wave; w++) woff += wsum[w];
  int excl = woff + s - tsum;
  int e0 = excl, e1 = e0 + v0, e2 = e1 + v1, e3 = e2 + v2;
  if (base + 3 < n) {
    *(int4*)(tmp + base) = make_int4(e0, e1, e2, e3);
  } else {
    if (base + 0 < n) tmp[base + 0] = e0;
    if (base + 1 < n) tmp[base + 1] = e1;
    if (base + 2 < n) tmp[base + 2] = e2;
    if (base + 3 < n) tmp[base + 3] = e3;
  }
  if (t == 255) bsum[b] = woff + s;
}

__global__ void rg_scan2(int* bsum, int* rowptr, int nb, int n) {
  int lane = threadIdx.x;
  int v = (lane < nb) ? bsum[lane] : 0;
  int s = v;
  for (int off = 1; off < 64; off <<= 1) {
    int u = __shfl_up(s, off);
    if (lane >= off) s += u;
  }
  if (lane < nb) bsum[lane] = s - v;
  if (lane == 63) rowptr[n] = s;
}

__global__ void rg_scan3(const int* bsum, int* rowptr, int* cursor, int n) {
  int b = blockIdx.x, t = threadIdx.x;
  int base = b * 1024 + t * 4;
  int off = bsum[b];
  if (base + 3 < n) {
    int4 v = *(const int4*)(cursor + base);
    int4 o = make_int4(v.x + off, v.y + off, v.z + off, v.w + off);
    *(int4*)(rowptr + base) = o;
    *(int4*)(cursor + base) = o;
  } else {
    for (int j = 0; j < 4; j++)
      if (base + j < n) {
        int o = cursor[base + j] + off;
        rowptr[base + j] = o;
        cursor[base + j] = o;
      }
  }
}

__global__ void rg_scatter(const int* d, int* cursor, int* perm) {
  int e = blockIdx.x * 256 + threadIdx.x;
  if (e < RG86_NE) perm[atomicAdd(&cursor[d[e]], 1)] = e;
}

// edge-parallel over CSR-permuted order: leaky-relu logit + fused (rel,src) index
__global__ void rg_edge(const int* perm, const int* src, const int* dst,
                        const int* et, const float* qd, const float* kd,
                        float* alphap, int* srcrel) {
  int i = blockIdx.x * 256 + threadIdx.x;
  if (i >= RG86_NE) return;
  int e = perm[i];
  int t = et[e], sv = src[e], dv = dst[e];
  float al = qd[t * RG86_NN + dv] + kd[t * RG86_NN + sv];
  al = al > 0.f ? al : 0.2f * al;
  alphap[i] = al;
  srcrel[i] = t * RG86_NN + sv;
}

// wave per node: lane-parallel segment softmax over contiguous alphap,
// then LDS-broadcast weighted row gather. out bf16.
__global__ void rg_agg(const int* rowptr, const float* alphap, const int* srcrel,
                       const unsigned short* xw, const float* bias,
                       unsigned short* out) {
  __shared__ float sw[4][64];
  __shared__ int ssrc[4][64];
  int lane = threadIdx.x & 63;
  int wv = threadIdx.x >> 6;
  int node = blockIdx.x * 4 + wv;
  if (node >= RG86_NN) return;
  int s0 = rowptr[node], s1 = rowptr[node + 1];
  int c0 = lane * 4;
  float a0 = 0.f, a1 = 0.f, a2 = 0.f, a3 = 0.f;
  if (s1 > s0) {
    float m = -1e30f;
    for (int bs = s0; bs < s1; bs += 64) {
      int i = bs + lane;
      float al = (i < s1) ? alphap[i] : -1e30f;
      m = fmaxf(m, al);
    }
    for (int o = 32; o >= 1; o >>= 1) m = fmaxf(m, __shfl_xor(m, o));
    float den = 0.f;
    for (int bs = s0; bs < s1; bs += 64) {
      int i = bs + lane;
      if (i < s1) den += __expf(alphap[i] - m);
    }
    for (int o = 32; o >= 1; o >>= 1) den += __shfl_xor(den, o);
    float inv = 1.f / (den + 1e-16f);
    for (int bs = s0; bs < s1; bs += 64) {
      int i = bs + lane;
      int nch = s1 - bs; if (nch > 64) nch = 64;
      float w = 0.f; int sr = 0;
      if (i < s1) { w = __expf(alphap[i] - m) * inv; sr = srcrel[i]; }
      sw[wv][lane] = w;
      ssrc[wv][lane] = sr;
#pragma unroll 4
      for (int j = 0; j < nch; j++) {
        float wj = sw[wv][j];
        ushort4 v = *(const ushort4*)(xw + (size_t)ssrc[wv][j] * RG86_HID + c0);
        a0 += wj * rg_b2f(v.x);
        a1 += wj * rg_b2f(v.y);
        a2 += wj * rg_b2f(v.z);
        a3 += wj * rg_b2f(v.w);
      }
    }
  }
  unsigned short* op = out + (size_t)node * RG86_HID + c0;
  op[0] = rg_f2b(a0 + bias[c0 + 0]);
  op[1] = rg_f2b(a1 + bias[c0 + 1]);
  op[2] = rg_f2b(a2 + bias[c0 + 2]);
  op[3] = rg_f2b(a3 + bias[c0 + 3]);
}

__global__ void rg_cls(const unsigned short* h4, const float* wc, const float* bc,
                       float* out) {
  int n = blockIdx.x * 256 + threadIdx.x;
  if (n >= RG86_NN) return;
  float a0 = bc[0], a1 = bc[1];
  const unsigned short* hr = h4 + (size_t)n * RG86_OUT;
  for (int j = 0; j < RG86_OUT; j++) {
    float h = rg_b2f(hr[j]);
    a0 += h * wc[j * 2 + 0];
    a1 += h * wc[j * 2 + 1];
  }
  out[n * 2 + 0] = a0;
  out[n * 2 + 1] = a1;
}

extern "C" void kernel_launch(void* const* d_in, const int* in_sizes, int n_in,
                              void* d_out, int out_size, void* d_ws, size_t ws_size,
                              hipStream_t stream) {
  (void)in_sizes; (void)n_in; (void)out_size;
  const float* x = (const float*)d_in[0];
  const int* ei = (const int*)d_in[1];
  const int* etp = (const int*)d_in[2];
  const float* w_in = (const float*)d_in[3];
  const float* b_in = (const float*)d_in[4];
  const float* c1w = (const float*)d_in[5];
  const float* c1q = (const float*)d_in[6];
  const float* c1k = (const float*)d_in[7];
  const float* c1b = (const float*)d_in[8];
  const float* c2w = (const float*)d_in[9];
  const float* c2q = (const float*)d_in[10];
  const float* c2k = (const float*)d_in[11];
  const float* c2b = (const float*)d_in[12];
  const float* w_out = (const float*)d_in[13];
  const float* b_out = (const float*)d_in[14];
  const float* w_cls = (const float*)d_in[15];
  const float* b_cls = (const float*)d_in[16];
  const int* esrc = ei;
  const int* edst = ei + RG86_NE;

  char* base = (char*)d_ws;
  size_t off = 0;
  unsigned short* xw = (unsigned short*)(base + off);
  off += (size_t)RG86_NR * RG86_NN * RG86_HID * 2;  // 76.8 MB
  unsigned short* h1b = (unsigned short*)(base + off); off += (size_t)RG86_NN * RG86_HID * 2;
  unsigned short* h2b = (unsigned short*)(base + off); off += (size_t)RG86_NN * RG86_HID * 2;
  unsigned short* h4b = (unsigned short*)(base + off); off += (size_t)RG86_NN * RG86_OUT * 2;
  unsigned short* w_inT = (unsigned short*)(base + off); off += (size_t)RG86_DIN * RG86_HID * 2;
  unsigned short* c1wT = (unsigned short*)(base + off); off += (size_t)RG86_NR * RG86_HID * RG86_HID * 2;
  unsigned short* c2wT = (unsigned short*)(base + off); off += (size_t)RG86_NR * RG86_HID * RG86_HID * 2;
  unsigned short* w_outT = (unsigned short*)(base + off); off += (size_t)RG86_HID * RG86_OUT * 2;
  float* qd = (float*)(base + off); off += (size_t)RG86_NR * RG86_NN * 4;
  float* kd = (float*)(base + off); off += (size_t)RG86_NR * RG86_NN * 4;
  float* wq1 = (float*)(base + off); off += (size_t)RG86_NR * RG86_HID * 4;
  float* wk1 = (float*)(base + off); off += (size_t)RG86_NR * RG86_HID * 4;
  float* wq2 = (float*)(base + off); off += (size_t)RG86_NR * RG86_HID * 4;
  float* wk2 = (float*)(base + off); off += (size_t)RG86_NR * RG86_HID * 4;
  int* counts = (int*)(base + off); off += (size_t)RG86_NN * 4;
  int* rowptr = (int*)(base + off); off += (size_t)(RG86_NN + 4) * 4;
  int* cursor = (int*)(base + off); off += (size_t)RG86_NN * 4;
  int* perm = (int*)(base + off); off += (size_t)RG86_NE * 4;
  int* bsum = (int*)(base + off); off += (size_t)64 * 4;
  float* alphap = (float*)(base + off); off += (size_t)RG86_NE * 4;
  int* srcrel = (int*)(base + off); off += (size_t)RG86_NE * 4;
  if (off > ws_size) return;

  int mt128 = (RG86_NN + 127) / 128;       // 391 m-tiles
  int nsb = (RG86_NN + 1023) / 1024;       // 49 scan blocks (<= 64)

  // weight preps
  rg_castT<<<(RG86_DIN * RG86_HID + 255) / 256, 256, 0, stream>>>(
      w_in, w_inT, RG86_DIN, RG86_HID);
  rg_castT3<<<(RG86_NR * RG86_HID * RG86_HID + 255) / 256, 256, 0, stream>>>(c1w, c1wT);
  rg_castT3<<<(RG86_NR * RG86_HID * RG86_HID + 255) / 256, 256, 0, stream>>>(c2w, c2wT);
  rg_castT<<<(RG86_HID * RG86_OUT + 255) / 256, 256, 0, stream>>>(
      w_out, w_outT, RG86_HID, RG86_OUT);
  rg_wqk<<<(RG86_NR * RG86_HID + 3) / 4, 256, 0, stream>>>(c1w, c1q, c1k, wq1, wk1);
  rg_wqk<<<(RG86_NR * RG86_HID + 3) / 4, 256, 0, stream>>>(c2w, c2q, c2k, wq2, wk2);

  // h1 = relu(x @ w_in + b_in), fp32 A staged async (double-buffered)
  rg_gemm2f<<<mt128 * 4, 256, 0, stream>>>(x, w_inT, b_in, h1b,
                                           RG86_NN, RG86_HID, RG86_DIN, 1);

  // CSR by dst (multi-block scan)
  hipMemsetAsync(counts, 0, (size_t)RG86_NN * 4, stream);
  rg_hist<<<(RG86_NE + 255) / 256, 256, 0, stream>>>(edst, counts);
  rg_scan1<<<nsb, 256, 0, stream>>>(counts, cursor, bsum, RG86_NN);
  rg_scan2<<<1, 64, 0, stream>>>(bsum, rowptr, nsb, RG86_NN);
  rg_scan3<<<nsb, 256, 0, stream>>>(bsum, rowptr, cursor, RG86_NN);
  rg_scatter<<<(RG86_NE + 255) / 256, 256, 0, stream>>>(edst, cursor, perm);

  // conv1: fused 3-relation GEMM (N=768, split output into xw[r][node][HID])
  rg_gemm2<<<mt128 * 12, 256, 0, stream>>>(h1b, c1wT, (const float*)0, xw,
                                           RG86_NN, RG86_NR * RG86_HID, RG86_HID, 0, 1);
  rg_qk2<<<(RG86_NN + 3) / 4, 256, 0, stream>>>(h1b, wq1, wk1, qd, kd);
  rg_edge<<<(RG86_NE + 255) / 256, 256, 0, stream>>>(perm, esrc, edst, etp, qd, kd,
                                                     alphap, srcrel);
  rg_agg<<<(RG86_NN + 3) / 4, 256, 0, stream>>>(rowptr, alphap, srcrel,
                                                xw, c1b, h2b);

  // conv2
  rg_gemm2<<<mt128 * 12, 256, 0, stream>>>(h2b, c2wT, (const float*)0, xw,
                                           RG86_NN, RG86_NR * RG86_HID, RG86_HID, 0, 1);
  rg_qk2<<<(RG86_NN + 3) / 4, 256, 0, stream>>>(h2b, wq2, wk2, qd, kd);
  rg_edge<<<(RG86_NE + 255) / 256, 256, 0, stream>>>(perm, esrc, edst, etp, qd, kd,
                                                     alphap, srcrel);
  rg_agg<<<(RG86_NN + 3) / 4, 256, 0, stream>>>(rowptr, alphap, srcrel,
                                                xw, c2b, h1b);

  // h4 = relu(h @ w_out + b_out)
  rg_gemm2<<<mt128, 256, 0, stream>>>(h1b, w_outT, b_out, h4b,
                                      RG86_NN, RG86_OUT, RG86_HID, 1, 0);

  // logits
  rg_cls<<<(RG86_NN + 255) / 256, 256, 0, stream>>>(h4b, w_cls, b_cls, (float*)d_out);
}

// Round 7
// 629.727 us; speedup vs baseline: 1.0226x; 1.0226x over previous
//
#include <hip/hip_runtime.h>
#include <hip/hip_bf16.h>

#define RG86_NN 50000
#define RG86_NE 320000
#define RG86_NR 3
#define RG86_DIN 768
#define RG86_HID 256
#define RG86_OUT 64

typedef __bf16 rg_bv8 __attribute__((ext_vector_type(8)));
typedef short rg_sv8 __attribute__((ext_vector_type(8)));
typedef float rg_fv4 __attribute__((ext_vector_type(4)));
typedef unsigned int rg_u32;

static __device__ float rg_b2f(unsigned short u) {
  return __uint_as_float(((unsigned int)u) << 16);
}
static __device__ unsigned short rg_f2b(float f) {
  unsigned int u = __float_as_uint(f);
  u += 0x7FFFu + ((u >> 16) & 1u);
  return (unsigned short)(u >> 16);
}

// async global->LDS, 16B per lane. lds arg must be the WAVE-uniform base;
// HW scatters lane l to base + l*16.
static __device__ __forceinline__ void rg_gl16(const void* g, void* lds_wave_base) {
  __builtin_amdgcn_global_load_lds(
      (const __attribute__((address_space(1))) rg_u32*)(unsigned long long)(uintptr_t)g,
      (__attribute__((address_space(3))) rg_u32*)(unsigned int)(uintptr_t)lds_wave_base,
      16, 0, 0);
}

__global__ void RGATModel_86371792322702_kernel() {}

// fp32 [rows][cols] -> bf16 [cols][rows]
__global__ void rg_castT(const float* in, unsigned short* out, int rows, int cols) {
  int i = blockIdx.x * 256 + threadIdx.x;
  if (i < rows * cols) {
    int r = i / cols, c = i % cols;
    out[(size_t)c * rows + r] = rg_f2b(in[i]);
  }
}

// 3-relation [256][256] transpose cast (one launch for a whole conv weight)
__global__ void rg_castT3(const float* in, unsigned short* out) {
  int i = blockIdx.x * 256 + threadIdx.x;
  if (i < RG86_NR * RG86_HID * RG86_HID) {
    int r = i >> 16, j = i & 65535;
    int row = j >> 8, col = j & 255;
    out[(r << 16) + (col << 8) + row] = rg_f2b(in[i]);
  }
}

// wq[r][c] = sum_o W[r][c][o]*q[o]; wk likewise. One wave per (r,c) row.
__global__ void rg_wqk(const float* W, const float* q, const float* k,
                       float* wq, float* wk) {
  int lane = threadIdx.x & 63;
  int p = blockIdx.x * 4 + (threadIdx.x >> 6);
  if (p >= RG86_NR * RG86_HID) return;
  const float* wr = W + (size_t)p * RG86_HID;
  float qv = 0.f, kv = 0.f;
  for (int j = lane; j < RG86_HID; j += 64) {
    float w = wr[j];
    qv += w * q[j];
    kv += w * k[j];
  }
  for (int o = 32; o >= 1; o >>= 1) { qv += __shfl_xor(qv, o); kv += __shfl_xor(kv, o); }
  if (lane == 0) { wq[p] = qv; wk[p] = kv; }
}

// qd[r][n] = h[n] . wq[r]  (identity: (h@W)q == h@(Wq)). Wave per node, 6 dots.
__global__ void rg_qk2(const unsigned short* h, const float* wq, const float* wk,
                       float* qd, float* kd) {
  int lane = threadIdx.x & 63;
  int n = blockIdx.x * 4 + (threadIdx.x >> 6);
  if (n >= RG86_NN) return;
  ushort4 hv = *(const ushort4*)(h + (size_t)n * RG86_HID + lane * 4);
  float h0 = rg_b2f(hv.x), h1 = rg_b2f(hv.y), h2 = rg_b2f(hv.z), h3 = rg_b2f(hv.w);
  float acc[6];
#pragma unroll
  for (int r = 0; r < RG86_NR; r++) {
    const float* wqr = wq + r * RG86_HID + lane * 4;
    const float* wkr = wk + r * RG86_HID + lane * 4;
    acc[r] = h0 * wqr[0] + h1 * wqr[1] + h2 * wqr[2] + h3 * wqr[3];
    acc[3 + r] = h0 * wkr[0] + h1 * wkr[1] + h2 * wkr[2] + h3 * wkr[3];
  }
#pragma unroll
  for (int j = 0; j < 6; j++)
    for (int o = 32; o >= 1; o >>= 1) acc[j] += __shfl_xor(acc[j], o);
  if (lane == 0) {
#pragma unroll
    for (int r = 0; r < RG86_NR; r++) {
      qd[r * RG86_NN + n] = acc[r];
      kd[r * RG86_NN + n] = acc[3 + r];
    }
  }
}

// MFMA GEMM, double-buffered with COUNTED vmcnt (T4): stage(next) stays in
// flight across the MFMA phase; only the previous tile's 6 loads are waited
// (vmcnt(6)). Raw s_barrier; never drain to 0 inside the loop.
// 128x64 tile, BK=64, XOR swizzle, XCD-bijective block swizzle, mt-major.
// split: N=768 fused 3-relation output -> C + (col>>8)*NN*256, stride 256.
__global__ __launch_bounds__(256) void rg_gemm2(
    const unsigned short* A, const unsigned short* Bt, const float* bias,
    unsigned short* C, int M, int N, int K, int relu, int split) {
  __shared__ unsigned short sA[2][128 * 64];
  __shared__ unsigned short sB[2][64 * 64];
  int tid = threadIdx.x;
  int wv = tid >> 6, lane = tid & 63;
  int nwg = gridDim.x;
  int q = nwg >> 3, rres = nwg & 7;
  int xcd = blockIdx.x & 7, jj = blockIdx.x >> 3;
  int wg = (xcd < rres ? xcd * (q + 1) : rres * (q + 1) + (xcd - rres) * q) + jj;
  int ntiles = N >> 6;
  int mt = wg / ntiles, nt = wg - mt * ntiles;
  int m0 = mt * 128, n0 = nt * 64;
  int frow = lane & 15, fhi = lane >> 4;
  int sr = tid >> 3, ss = tid & 7;
  rg_fv4 acc[2][4] = {};

  auto stage = [&](int buf, int k0) {
#pragma unroll
    for (int i = 0; i < 4; i++) {
      int r = i * 32 + sr;
      int gr = m0 + r;
      if (gr >= M) gr = M - 1;
      const unsigned short* gp = A + (size_t)gr * K + k0 + ((ss ^ (r & 7)) << 3);
      rg_gl16(gp, (char*)sA[buf] + (size_t)(i * 256 + wv * 64) * 16);
    }
#pragma unroll
    for (int i = 0; i < 2; i++) {
      int r = i * 32 + sr;
      const unsigned short* gp = Bt + (size_t)(n0 + r) * K + k0 + ((ss ^ (r & 7)) << 3);
      rg_gl16(gp, (char*)sB[buf] + (size_t)(i * 256 + wv * 64) * 16);
    }
  };

  int nst = K >> 6;
  stage(0, 0);
  int cur = 0;
  for (int t = 0; t < nst; t++) {
    if (t + 1 < nst) {
      stage(cur ^ 1, (t + 1) << 6);
      asm volatile("s_waitcnt vmcnt(6)" ::: "memory");  // prev tile landed; next in flight
    } else {
      asm volatile("s_waitcnt vmcnt(0)" ::: "memory");
    }
    __builtin_amdgcn_s_barrier();
    __builtin_amdgcn_sched_barrier(0);
#pragma unroll
    for (int ks = 0; ks < 2; ks++) {
      rg_bv8 af[2], bf[4];
#pragma unroll
      for (int mf = 0; mf < 2; mf++) {
        int r = wv * 32 + mf * 16 + frow;
        int slot = (ks * 4 + fhi) ^ (r & 7);
        af[mf] = *(const rg_bv8*)((const char*)sA[cur] + r * 128 + slot * 16);
      }
#pragma unroll
      for (int nf = 0; nf < 4; nf++) {
        int r = nf * 16 + frow;
        int slot = (ks * 4 + fhi) ^ (r & 7);
        bf[nf] = *(const rg_bv8*)((const char*)sB[cur] + r * 128 + slot * 16);
      }
#pragma unroll
      for (int mf = 0; mf < 2; mf++)
#pragma unroll
        for (int nf = 0; nf < 4; nf++)
          acc[mf][nf] = __builtin_amdgcn_mfma_f32_16x16x32_bf16(af[mf], bf[nf],
                                                                acc[mf][nf], 0, 0, 0);
    }
    __builtin_amdgcn_s_barrier();  // reads of buf[cur] done before next overwrite
    cur ^= 1;
  }
#pragma unroll
  for (int mf = 0; mf < 2; mf++) {
#pragma unroll
    for (int nf = 0; nf < 4; nf++) {
      int col = n0 + nf * 16 + frow;
      float bv = bias ? bias[col] : 0.f;
#pragma unroll
      for (int r = 0; r < 4; r++) {
        int row = m0 + wv * 32 + mf * 16 + fhi * 4 + r;
        if (row < M) {
          float v = acc[mf][nf][r] + bv;
          if (relu && v < 0.f) v = 0.f;
          if (split)
            C[((size_t)(col >> 8) * RG86_NN + row) * 256 + (col & 255)] = rg_f2b(v);
          else
            C[(size_t)row * N + col] = rg_f2b(v);
        }
      }
    }
  }
}

// fp32-A GEMM, double-buffered with counted vmcnt like rg_gemm2 (10 loads per
// wave per stage). A staged fp32 via global_load_lds (32B-slot XOR swizzle),
// converted bf16 at fragment load.
__global__ __launch_bounds__(256) void rg_gemm2f(
    const float* A, const unsigned short* Bt, const float* bias,
    unsigned short* C, int M, int N, int K, int relu) {
  __shared__ float sA[2][128 * 64];          // 2 x 32 KB
  __shared__ unsigned short sB[2][64 * 64];  // 2 x 8 KB
  int tid = threadIdx.x;
  int wv = tid >> 6, lane = tid & 63;
  int nwg = gridDim.x;
  int q = nwg >> 3, rres = nwg & 7;
  int xcd = blockIdx.x & 7, jj = blockIdx.x >> 3;
  int wg = (xcd < rres ? xcd * (q + 1) : rres * (q + 1) + (xcd - rres) * q) + jj;
  int ntiles = N >> 6;
  int mt = wg / ntiles, nt = wg - mt * ntiles;
  int m0 = mt * 128, n0 = nt * 64;
  int frow = lane & 15, fhi = lane >> 4;
  int sr8 = tid >> 3, ss8 = tid & 7;
  int sr16 = tid >> 4, hs = tid & 15;
  rg_fv4 acc[2][4] = {};

  auto stage = [&](int buf, int k0) {
#pragma unroll
    for (int i = 0; i < 2; i++) {
      int r = i * 32 + sr8;
      const unsigned short* gp = Bt + (size_t)(n0 + r) * K + k0 + ((ss8 ^ (r & 7)) << 3);
      rg_gl16(gp, (char*)sB[buf] + (size_t)(i * 256 + wv * 64) * 16);
    }
#pragma unroll
    for (int i = 0; i < 8; i++) {
      int r = i * 16 + sr16;
      int gr = m0 + r;
      if (gr >= M) gr = M - 1;
      const float* gp = A + (size_t)gr * K + k0 +
                        ((((hs >> 1) ^ (r & 7)) << 3) + ((hs & 1) << 2));
      rg_gl16(gp, (char*)sA[buf] + (size_t)(i * 256 + wv * 64) * 16);
    }
  };

  int nst = K >> 6;
  stage(0, 0);
  int cur = 0;
  for (int t = 0; t < nst; t++) {
    if (t + 1 < nst) {
      stage(cur ^ 1, (t + 1) << 6);
      asm volatile("s_waitcnt vmcnt(10)" ::: "memory");
    } else {
      asm volatile("s_waitcnt vmcnt(0)" ::: "memory");
    }
    __builtin_amdgcn_s_barrier();
    __builtin_amdgcn_sched_barrier(0);
#pragma unroll
    for (int ks = 0; ks < 2; ks++) {
      rg_bv8 af[2], bf[4];
#pragma unroll
      for (int mf = 0; mf < 2; mf++) {
        int r = wv * 32 + mf * 16 + frow;
        int sp = (ks * 4 + fhi) ^ (r & 7);
        const float* ap = sA[cur] + r * 64 + sp * 8;
        float4 f0 = *(const float4*)ap;
        float4 f1 = *(const float4*)(ap + 4);
        rg_sv8 av;
        av[0] = (short)rg_f2b(f0.x); av[1] = (short)rg_f2b(f0.y);
        av[2] = (short)rg_f2b(f0.z); av[3] = (short)rg_f2b(f0.w);
        av[4] = (short)rg_f2b(f1.x); av[5] = (short)rg_f2b(f1.y);
        av[6] = (short)rg_f2b(f1.z); av[7] = (short)rg_f2b(f1.w);
        af[mf] = *(rg_bv8*)&av;
      }
#pragma unroll
      for (int nf = 0; nf < 4; nf++) {
        int r = nf * 16 + frow;
        int slot = (ks * 4 + fhi) ^ (r & 7);
        bf[nf] = *(const rg_bv8*)((const char*)sB[cur] + r * 128 + slot * 16);
      }
#pragma unroll
      for (int mf = 0; mf < 2; mf++)
#pragma unroll
        for (int nf = 0; nf < 4; nf++)
          acc[mf][nf] = __builtin_amdgcn_mfma_f32_16x16x32_bf16(af[mf], bf[nf],
                                                                acc[mf][nf], 0, 0, 0);
    }
    __builtin_amdgcn_s_barrier();
    cur ^= 1;
  }
#pragma unroll
  for (int mf = 0; mf < 2; mf++) {
#pragma unroll
    for (int nf = 0; nf < 4; nf++) {
      int col = n0 + nf * 16 + frow;
      float bv = bias ? bias[col] : 0.f;
#pragma unroll
      for (int r = 0; r < 4; r++) {
        int row = m0 + wv * 32 + mf * 16 + fhi * 4 + r;
        if (row < M) {
          float v = acc[mf][nf][r] + bv;
          if (relu && v < 0.f) v = 0.f;
          C[(size_t)row * N + col] = rg_f2b(v);
        }
      }
    }
  }
}

__global__ void rg_hist(const int* d, int* counts) {
  int e = blockIdx.x * 256 + threadIdx.x;
  if (e < RG86_NE) atomicAdd(&counts[d[e]], 1);
}

// ---- multi-block exclusive scan of counts[n] -> rowptr/cursor ----
__global__ void rg_scan1(const int* counts, int* tmp, int* bsum, int n) {
  int b = blockIdx.x, t = threadIdx.x;
  int base = b * 1024 + t * 4;
  int v0 = 0, v1 = 0, v2 = 0, v3 = 0;
  if (base + 3 < n) {
    int4 v = *(const int4*)(counts + base);
    v0 = v.x; v1 = v.y; v2 = v.z; v3 = v.w;
  } else {
    if (base + 0 < n) v0 = counts[base + 0];
    if (base + 1 < n) v1 = counts[base + 1];
    if (base + 2 < n) v2 = counts[base + 2];
    if (base + 3 < n) v3 = counts[base + 3];
  }
  int tsum = v0 + v1 + v2 + v3;
  int lane = t & 63, wave = t >> 6;
  int s = tsum;
  for (int off = 1; off < 64; off <<= 1) {
    int u = __shfl_up(s, off);
    if (lane >= off) s += u;
  }
  __shared__ int wsum[4];
  if (lane == 63) wsum[wave] = s;
  __syncthreads();
  int woff = 0;
  for (int w = 0; w < wave; w++) woff += wsum[w];
  int excl = woff + s - tsum;
  int e0 = excl, e1 = e0 + v0, e2 = e1 + v1, e3 = e2 + v2;
  if (base + 3 < n) {
    *(int4*)(tmp + base) = make_int4(e0, e1, e2, e3);
  } else {
    if (base + 0 < n) tmp[base + 0] = e0;
    if (base + 1 < n) tmp[base + 1] = e1;
    if (base + 2 < n) tmp[base + 2] = e2;
    if (base + 3 < n) tmp[base + 3] = e3;
  }
  if (t == 255) bsum[b] = woff + s;
}

__global__ void rg_scan2(int* bsum, int* rowptr, int nb, int n) {
  int lane = threadIdx.x;
  int v = (lane < nb) ? bsum[lane] : 0;
  int s = v;
  for (int off = 1; off < 64; off <<= 1) {
    int u = __shfl_up(s, off);
    if (lane >= off) s += u;
  }
  if (lane < nb) bsum[lane] = s - v;
  if (lane == 63) rowptr[n] = s;
}

__global__ void rg_scan3(const int* bsum, int* rowptr, int* cursor, int n) {
  int b = blockIdx.x, t = threadIdx.x;
  int base = b * 1024 + t * 4;
  int off = bsum[b];
  if (base + 3 < n) {
    int4 v = *(const int4*)(cursor + base);
    int4 o = make_int4(v.x + off, v.y + off, v.z + off, v.w + off);
    *(int4*)(rowptr + base) = o;
    *(int4*)(cursor + base) = o;
  } else {
    for (int j = 0; j < 4; j++)
      if (base + j < n) {
        int o = cursor[base + j] + off;
        rowptr[base + j] = o;
        cursor[base + j] = o;
      }
  }
}

__global__ void rg_scatter(const int* d, int* cursor, int* perm) {
  int e = blockIdx.x * 256 + threadIdx.x;
  if (e < RG86_NE) perm[atomicAdd(&cursor[d[e]], 1)] = e;
}

// edge-parallel over CSR-permuted order: leaky-relu logit + fused (rel,src) index
__global__ void rg_edge(const int* perm, const int* src, const int* dst,
                        const int* et, const float* qd, const float* kd,
                        float* alphap, int* srcrel) {
  int i = blockIdx.x * 256 + threadIdx.x;
  if (i >= RG86_NE) return;
  int e = perm[i];
  int t = et[e], sv = src[e], dv = dst[e];
  float al = qd[t * RG86_NN + dv] + kd[t * RG86_NN + sv];
  al = al > 0.f ? al : 0.2f * al;
  alphap[i] = al;
  srcrel[i] = t * RG86_NN + sv;
}

// wave per node: lane-parallel segment softmax over contiguous alphap,
// then LDS-broadcast weighted row gather. out bf16.
__global__ void rg_agg(const int* rowptr, const float* alphap, const int* srcrel,
                       const unsigned short* xw, const float* bias,
                       unsigned short* out) {
  __shared__ float sw[4][64];
  __shared__ int ssrc[4][64];
  int lane = threadIdx.x & 63;
  int wv = threadIdx.x >> 6;
  int node = blockIdx.x * 4 + wv;
  if (node >= RG86_NN) return;
  int s0 = rowptr[node], s1 = rowptr[node + 1];
  int c0 = lane * 4;
  float a0 = 0.f, a1 = 0.f, a2 = 0.f, a3 = 0.f;
  if (s1 > s0) {
    float m = -1e30f;
    for (int bs = s0; bs < s1; bs += 64) {
      int i = bs + lane;
      float al = (i < s1) ? alphap[i] : -1e30f;
      m = fmaxf(m, al);
    }
    for (int o = 32; o >= 1; o >>= 1) m = fmaxf(m, __shfl_xor(m, o));
    float den = 0.f;
    for (int bs = s0; bs < s1; bs += 64) {
      int i = bs + lane;
      if (i < s1) den += __expf(alphap[i] - m);
    }
    for (int o = 32; o >= 1; o >>= 1) den += __shfl_xor(den, o);
    float inv = 1.f / (den + 1e-16f);
    for (int bs = s0; bs < s1; bs += 64) {
      int i = bs + lane;
      int nch = s1 - bs; if (nch > 64) nch = 64;
      float w = 0.f; int sr = 0;
      if (i < s1) { w = __expf(alphap[i] - m) * inv; sr = srcrel[i]; }
      sw[wv][lane] = w;
      ssrc[wv][lane] = sr;
#pragma unroll 4
      for (int j = 0; j < nch; j++) {
        float wj = sw[wv][j];
        ushort4 v = *(const ushort4*)(xw + (size_t)ssrc[wv][j] * RG86_HID + c0);
        a0 += wj * rg_b2f(v.x);
        a1 += wj * rg_b2f(v.y);
        a2 += wj * rg_b2f(v.z);
        a3 += wj * rg_b2f(v.w);
      }
    }
  }
  unsigned short* op = out + (size_t)node * RG86_HID + c0;
  op[0] = rg_f2b(a0 + bias[c0 + 0]);
  op[1] = rg_f2b(a1 + bias[c0 + 1]);
  op[2] = rg_f2b(a2 + bias[c0 + 2]);
  op[3] = rg_f2b(a3 + bias[c0 + 3]);
}

__global__ void rg_cls(const unsigned short* h4, const float* wc, const float* bc,
                       float* out) {
  int n = blockIdx.x * 256 + threadIdx.x;
  if (n >= RG86_NN) return;
  float a0 = bc[0], a1 = bc[1];
  const unsigned short* hr = h4 + (size_t)n * RG86_OUT;
  for (int j = 0; j < RG86_OUT; j++) {
    float h = rg_b2f(hr[j]);
    a0 += h * wc[j * 2 + 0];
    a1 += h * wc[j * 2 + 1];
  }
  out[n * 2 + 0] = a0;
  out[n * 2 + 1] = a1;
}

extern "C" void kernel_launch(void* const* d_in, const int* in_sizes, int n_in,
                              void* d_out, int out_size, void* d_ws, size_t ws_size,
                              hipStream_t stream) {
  (void)in_sizes; (void)n_in; (void)out_size;
  const float* x = (const float*)d_in[0];
  const int* ei = (const int*)d_in[1];
  const int* etp = (const int*)d_in[2];
  const float* w_in = (const float*)d_in[3];
  const float* b_in = (const float*)d_in[4];
  const float* c1w = (const float*)d_in[5];
  const float* c1q = (const float*)d_in[6];
  const float* c1k = (const float*)d_in[7];
  const float* c1b = (const float*)d_in[8];
  const float* c2w = (const float*)d_in[9];
  const float* c2q = (const float*)d_in[10];
  const float* c2k = (const float*)d_in[11];
  const float* c2b = (const float*)d_in[12];
  const float* w_out = (const float*)d_in[13];
  const float* b_out = (const float*)d_in[14];
  const float* w_cls = (const float*)d_in[15];
  const float* b_cls = (const float*)d_in[16];
  const int* esrc = ei;
  const int* edst = ei + RG86_NE;

  char* base = (char*)d_ws;
  size_t off = 0;
  unsigned short* xw = (unsigned short*)(base + off);
  off += (size_t)RG86_NR * RG86_NN * RG86_HID * 2;  // 76.8 MB
  unsigned short* h1b = (unsigned short*)(base + off); off += (size_t)RG86_NN * RG86_HID * 2;
  unsigned short* h2b = (unsigned short*)(base + off); off += (size_t)RG86_NN * RG86_HID * 2;
  unsigned short* h4b = (unsigned short*)(base + off); off += (size_t)RG86_NN * RG86_OUT * 2;
  unsigned short* w_inT = (unsigned short*)(base + off); off += (size_t)RG86_DIN * RG86_HID * 2;
  unsigned short* c1wT = (unsigned short*)(base + off); off += (size_t)RG86_NR * RG86_HID * RG86_HID * 2;
  unsigned short* c2wT = (unsigned short*)(base + off); off += (size_t)RG86_NR * RG86_HID * RG86_HID * 2;
  unsigned short* w_outT = (unsigned short*)(base + off); off += (size_t)RG86_HID * RG86_OUT * 2;
  float* qd = (float*)(base + off); off += (size_t)RG86_NR * RG86_NN * 4;
  float* kd = (float*)(base + off); off += (size_t)RG86_NR * RG86_NN * 4;
  float* wq1 = (float*)(base + off); off += (size_t)RG86_NR * RG86_HID * 4;
  float* wk1 = (float*)(base + off); off += (size_t)RG86_NR * RG86_HID * 4;
  float* wq2 = (float*)(base + off); off += (size_t)RG86_NR * RG86_HID * 4;
  float* wk2 = (float*)(base + off); off += (size_t)RG86_NR * RG86_HID * 4;
  int* counts = (int*)(base + off); off += (size_t)RG86_NN * 4;
  int* rowptr = (int*)(base + off); off += (size_t)(RG86_NN + 4) * 4;
  int* cursor = (int*)(base + off); off += (size_t)RG86_NN * 4;
  int* perm = (int*)(base + off); off += (size_t)RG86_NE * 4;
  int* bsum = (int*)(base + off); off += (size_t)64 * 4;
  float* alphap = (float*)(base + off); off += (size_t)RG86_NE * 4;
  int* srcrel = (int*)(base + off); off += (size_t)RG86_NE * 4;
  if (off > ws_size) return;

  int mt128 = (RG86_NN + 127) / 128;       // 391 m-tiles
  int nsb = (RG86_NN + 1023) / 1024;       // 49 scan blocks (<= 64)

  // weight preps
  rg_castT<<<(RG86_DIN * RG86_HID + 255) / 256, 256, 0, stream>>>(
      w_in, w_inT, RG86_DIN, RG86_HID);
  rg_castT3<<<(RG86_NR * RG86_HID * RG86_HID + 255) / 256, 256, 0, stream>>>(c1w, c1wT);
  rg_castT3<<<(RG86_NR * RG86_HID * RG86_HID + 255) / 256, 256, 0, stream>>>(c2w, c2wT);
  rg_castT<<<(RG86_HID * RG86_OUT + 255) / 256, 256, 0, stream>>>(
      w_out, w_outT, RG86_HID, RG86_OUT);
  rg_wqk<<<(RG86_NR * RG86_HID + 3) / 4, 256, 0, stream>>>(c1w, c1q, c1k, wq1, wk1);
  rg_wqk<<<(RG86_NR * RG86_HID + 3) / 4, 256, 0, stream>>>(c2w, c2q, c2k, wq2, wk2);

  // h1 = relu(x @ w_in + b_in), fp32 A staged async (counted-vmcnt pipeline)
  rg_gemm2f<<<mt128 * 4, 256, 0, stream>>>(x, w_inT, b_in, h1b,
                                           RG86_NN, RG86_HID, RG86_DIN, 1);

  // CSR by dst (multi-block scan)
  hipMemsetAsync(counts, 0, (size_t)RG86_NN * 4, stream);
  rg_hist<<<(RG86_NE + 255) / 256, 256, 0, stream>>>(edst, counts);
  rg_scan1<<<nsb, 256, 0, stream>>>(counts, cursor, bsum, RG86_NN);
  rg_scan2<<<1, 64, 0, stream>>>(bsum, rowptr, nsb, RG86_NN);
  rg_scan3<<<nsb, 256, 0, stream>>>(bsum, rowptr, cursor, RG86_NN);
  rg_scatter<<<(RG86_NE + 255) / 256, 256, 0, stream>>>(edst, cursor, perm);

  // conv1: fused 3-relation GEMM (N=768, split output into xw[r][node][HID])
  rg_gemm2<<<mt128 * 12, 256, 0, stream>>>(h1b, c1wT, (const float*)0, xw,
                                           RG86_NN, RG86_NR * RG86_HID, RG86_HID, 0, 1);
  rg_qk2<<<(RG86_NN + 3) / 4, 256, 0, stream>>>(h1b, wq1, wk1, qd, kd);
  rg_edge<<<(RG86_NE + 255) / 256, 256, 0, stream>>>(perm, esrc, edst, etp, qd, kd,
                                                     alphap, srcrel);
  rg_agg<<<(RG86_NN + 3) / 4, 256, 0, stream>>>(rowptr, alphap, srcrel,
                                                xw, c1b, h2b);

  // conv2
  rg_gemm2<<<mt128 * 12, 256, 0, stream>>>(h2b, c2wT, (const float*)0, xw,
                                           RG86_NN, RG86_NR * RG86_HID, RG86_HID, 0, 1);
  rg_qk2<<<(RG86_NN + 3) / 4, 256, 0, stream>>>(h2b, wq2, wk2, qd, kd);
  rg_edge<<<(RG86_NE + 255) / 256, 256, 0, stream>>>(perm, esrc, edst, etp, qd, kd,
                                                     alphap, srcrel);
  rg_agg<<<(RG86_NN + 3) / 4, 256, 0, stream>>>(rowptr, alphap, srcrel,
                                                xw, c2b, h1b);

  // h4 = relu(h @ w_out + b_out)
  rg_gemm2<<<mt128, 256, 0, stream>>>(h1b, w_outT, b_out, h4b,
                                      RG86_NN, RG86_OUT, RG86_HID, 1, 0);

  // logits
  rg_cls<<<(RG86_NN + 255) / 256, 256, 0, stream>>>(h4b, w_cls, b_cls, (float*)d_out);
}

// Round 8
// 571.333 us; speedup vs baseline: 1.1271x; 1.1022x over previous
//
#include <hip/hip_runtime.h>
#include <hip/hip_bf16.h>

#define RG86_NN 50000
#define RG86_NE 320000
#define RG86_NR 3
#define RG86_DIN 768
#define RG86_HID 256
#define RG86_OUT 64

typedef __bf16 rg_bv8 __attribute__((ext_vector_type(8)));
typedef short rg_sv8 __attribute__((ext_vector_type(8)));
typedef float rg_fv4 __attribute__((ext_vector_type(4)));
typedef unsigned int rg_u32;

static __device__ float rg_b2f(unsigned short u) {
  return __uint_as_float(((unsigned int)u) << 16);
}
static __device__ unsigned short rg_f2b(float f) {
  unsigned int u = __float_as_uint(f);
  u += 0x7FFFu + ((u >> 16) & 1u);
  return (unsigned short)(u >> 16);
}

// async global->LDS, 16B per lane. lds arg must be the WAVE-uniform base;
// HW scatters lane l to base + l*16.
static __device__ __forceinline__ void rg_gl16(const void* g, void* lds_wave_base) {
  __builtin_amdgcn_global_load_lds(
      (const __attribute__((address_space(1))) rg_u32*)(unsigned long long)(uintptr_t)g,
      (__attribute__((address_space(3))) rg_u32*)(unsigned int)(uintptr_t)lds_wave_base,
      16, 0, 0);
}

__global__ void RGATModel_86371792322702_kernel() {}

// fp32 [rows][cols] -> bf16 [cols][rows]
__global__ void rg_castT(const float* in, unsigned short* out, int rows, int cols) {
  int i = blockIdx.x * 256 + threadIdx.x;
  if (i < rows * cols) {
    int r = i / cols, c = i % cols;
    out[(size_t)c * rows + r] = rg_f2b(in[i]);
  }
}

// 3-relation [256][256] transpose cast (one launch for a whole conv weight)
__global__ void rg_castT3(const float* in, unsigned short* out) {
  int i = blockIdx.x * 256 + threadIdx.x;
  if (i < RG86_NR * RG86_HID * RG86_HID) {
    int r = i >> 16, j = i & 65535;
    int row = j >> 8, col = j & 255;
    out[(r << 16) + (col << 8) + row] = rg_f2b(in[i]);
  }
}

// wq[r][c] = sum_o W[r][c][o]*q[o]; wk likewise. One wave per (r,c) row.
__global__ void rg_wqk(const float* W, const float* q, const float* k,
                       float* wq, float* wk) {
  int lane = threadIdx.x & 63;
  int p = blockIdx.x * 4 + (threadIdx.x >> 6);
  if (p >= RG86_NR * RG86_HID) return;
  const float* wr = W + (size_t)p * RG86_HID;
  float qv = 0.f, kv = 0.f;
  for (int j = lane; j < RG86_HID; j += 64) {
    float w = wr[j];
    qv += w * q[j];
    kv += w * k[j];
  }
  for (int o = 32; o >= 1; o >>= 1) { qv += __shfl_xor(qv, o); kv += __shfl_xor(kv, o); }
  if (lane == 0) { wq[p] = qv; wk[p] = kv; }
}

// qd[r][n] = h[n] . wq[r]  (identity: (h@W)q == h@(Wq)). Wave per node, 6 dots.
__global__ void rg_qk2(const unsigned short* h, const float* wq, const float* wk,
                       float* qd, float* kd) {
  int lane = threadIdx.x & 63;
  int n = blockIdx.x * 4 + (threadIdx.x >> 6);
  if (n >= RG86_NN) return;
  ushort4 hv = *(const ushort4*)(h + (size_t)n * RG86_HID + lane * 4);
  float h0 = rg_b2f(hv.x), h1 = rg_b2f(hv.y), h2 = rg_b2f(hv.z), h3 = rg_b2f(hv.w);
  float acc[6];
#pragma unroll
  for (int r = 0; r < RG86_NR; r++) {
    const float* wqr = wq + r * RG86_HID + lane * 4;
    const float* wkr = wk + r * RG86_HID + lane * 4;
    acc[r] = h0 * wqr[0] + h1 * wqr[1] + h2 * wqr[2] + h3 * wqr[3];
    acc[3 + r] = h0 * wkr[0] + h1 * wkr[1] + h2 * wkr[2] + h3 * wkr[3];
  }
#pragma unroll
  for (int j = 0; j < 6; j++)
    for (int o = 32; o >= 1; o >>= 1) acc[j] += __shfl_xor(acc[j], o);
  if (lane == 0) {
#pragma unroll
    for (int r = 0; r < RG86_NR; r++) {
      qd[r * RG86_NN + n] = acc[r];
      kd[r * RG86_NN + n] = acc[3 + r];
    }
  }
}

// MFMA GEMM (R4-proven single-buffer 1-phase): 128x64 tile, BK=64,
// global_load_lds + XOR swizzle, XCD-bijective block swizzle, mt-major.
// Used for the h4 GEMM (N=64).
__global__ __launch_bounds__(256) void rg_gemm2(
    const unsigned short* A, const unsigned short* Bt, const float* bias,
    unsigned short* C, int M, int N, int K, int relu, int split) {
  __shared__ unsigned short sA[128 * 64];
  __shared__ unsigned short sB[64 * 64];
  int tid = threadIdx.x;
  int wv = tid >> 6, lane = tid & 63;
  int nwg = gridDim.x;
  int q = nwg >> 3, rres = nwg & 7;
  int xcd = blockIdx.x & 7, jj = blockIdx.x >> 3;
  int wg = (xcd < rres ? xcd * (q + 1) : rres * (q + 1) + (xcd - rres) * q) + jj;
  int ntiles = N >> 6;
  int mt = wg / ntiles, nt = wg - mt * ntiles;
  int m0 = mt * 128, n0 = nt * 64;
  int frow = lane & 15, fhi = lane >> 4;
  rg_fv4 acc[2][4] = {};
  for (int k0 = 0; k0 < K; k0 += 64) {
#pragma unroll
    for (int i = 0; i < 4; i++) {
      int idx = i * 256 + tid;
      int r = idx >> 3, s = idx & 7;
      int gr = m0 + r;
      if (gr >= M) gr = M - 1;
      const unsigned short* gp = A + (size_t)gr * K + k0 + ((s ^ (r & 7)) << 3);
      rg_gl16(gp, (char*)sA + (size_t)(i * 256 + wv * 64) * 16);
    }
#pragma unroll
    for (int i = 0; i < 2; i++) {
      int idx = i * 256 + tid;
      int r = idx >> 3, s = idx & 7;
      const unsigned short* gp = Bt + (size_t)(n0 + r) * K + k0 + ((s ^ (r & 7)) << 3);
      rg_gl16(gp, (char*)sB + (size_t)(i * 256 + wv * 64) * 16);
    }
    __syncthreads();
#pragma unroll
    for (int ks = 0; ks < 2; ks++) {
      rg_bv8 af[2], bf[4];
#pragma unroll
      for (int mf = 0; mf < 2; mf++) {
        int r = wv * 32 + mf * 16 + frow;
        int slot = (ks * 4 + fhi) ^ (r & 7);
        af[mf] = *(const rg_bv8*)((const char*)sA + r * 128 + slot * 16);
      }
#pragma unroll
      for (int nf = 0; nf < 4; nf++) {
        int r = nf * 16 + frow;
        int slot = (ks * 4 + fhi) ^ (r & 7);
        bf[nf] = *(const rg_bv8*)((const char*)sB + r * 128 + slot * 16);
      }
#pragma unroll
      for (int mf = 0; mf < 2; mf++)
#pragma unroll
        for (int nf = 0; nf < 4; nf++)
          acc[mf][nf] = __builtin_amdgcn_mfma_f32_16x16x32_bf16(af[mf], bf[nf],
                                                                acc[mf][nf], 0, 0, 0);
    }
    __syncthreads();
  }
#pragma unroll
  for (int mf = 0; mf < 2; mf++) {
#pragma unroll
    for (int nf = 0; nf < 4; nf++) {
      int col = n0 + nf * 16 + frow;
      float bv = bias ? bias[col] : 0.f;
#pragma unroll
      for (int r = 0; r < 4; r++) {
        int row = m0 + wv * 32 + mf * 16 + fhi * 4 + r;
        if (row < M) {
          float v = acc[mf][nf][r] + bv;
          if (relu && v < 0.f) v = 0.f;
          if (split)
            C[((size_t)(col >> 8) * RG86_NN + row) * 256 + (col & 255)] = rg_f2b(v);
          else
            C[(size_t)row * N + col] = rg_f2b(v);
        }
      }
    }
  }
}

// Wide MFMA GEMM: 128x128 tile, BK=64, single-buffer 1-phase. 32 MFMA per
// K-step per wave (2x the 64-wide version) -> more compute per barrier drain.
// LDS 32 KB -> 5 blocks/CU. Used for the conv GEMMs (N=768, split output).
__global__ __launch_bounds__(256) void rg_gemm2w(
    const unsigned short* A, const unsigned short* Bt,
    unsigned short* C, int M, int N, int K) {
  __shared__ unsigned short sA[128 * 64];
  __shared__ unsigned short sB[128 * 64];
  int tid = threadIdx.x;
  int wv = tid >> 6, lane = tid & 63;
  int nwg = gridDim.x;
  int q = nwg >> 3, rres = nwg & 7;
  int xcd = blockIdx.x & 7, jj = blockIdx.x >> 3;
  int wg = (xcd < rres ? xcd * (q + 1) : rres * (q + 1) + (xcd - rres) * q) + jj;
  int ntiles = N >> 7;
  int mt = wg / ntiles, nt = wg - mt * ntiles;
  int m0 = mt * 128, n0 = nt * 128;
  int frow = lane & 15, fhi = lane >> 4;
  rg_fv4 acc[2][8] = {};
  for (int k0 = 0; k0 < K; k0 += 64) {
#pragma unroll
    for (int i = 0; i < 4; i++) {
      int idx = i * 256 + tid;
      int r = idx >> 3, s = idx & 7;
      int gr = m0 + r;
      if (gr >= M) gr = M - 1;
      const unsigned short* gp = A + (size_t)gr * K + k0 + ((s ^ (r & 7)) << 3);
      rg_gl16(gp, (char*)sA + (size_t)(i * 256 + wv * 64) * 16);
    }
#pragma unroll
    for (int i = 0; i < 4; i++) {
      int idx = i * 256 + tid;
      int r = idx >> 3, s = idx & 7;
      const unsigned short* gp = Bt + (size_t)(n0 + r) * K + k0 + ((s ^ (r & 7)) << 3);
      rg_gl16(gp, (char*)sB + (size_t)(i * 256 + wv * 64) * 16);
    }
    __syncthreads();
#pragma unroll
    for (int ks = 0; ks < 2; ks++) {
      rg_bv8 af[2], bf[8];
#pragma unroll
      for (int mf = 0; mf < 2; mf++) {
        int r = wv * 32 + mf * 16 + frow;
        int slot = (ks * 4 + fhi) ^ (r & 7);
        af[mf] = *(const rg_bv8*)((const char*)sA + r * 128 + slot * 16);
      }
#pragma unroll
      for (int nf = 0; nf < 8; nf++) {
        int r = nf * 16 + frow;
        int slot = (ks * 4 + fhi) ^ (r & 7);
        bf[nf] = *(const rg_bv8*)((const char*)sB + r * 128 + slot * 16);
      }
#pragma unroll
      for (int mf = 0; mf < 2; mf++)
#pragma unroll
        for (int nf = 0; nf < 8; nf++)
          acc[mf][nf] = __builtin_amdgcn_mfma_f32_16x16x32_bf16(af[mf], bf[nf],
                                                                acc[mf][nf], 0, 0, 0);
    }
    __syncthreads();
  }
  // split epilogue: col -> relation (col>>8), inner col&255
#pragma unroll
  for (int mf = 0; mf < 2; mf++) {
#pragma unroll
    for (int nf = 0; nf < 8; nf++) {
      int col = n0 + nf * 16 + frow;
#pragma unroll
      for (int r = 0; r < 4; r++) {
        int row = m0 + wv * 32 + mf * 16 + fhi * 4 + r;
        if (row < M)
          C[((size_t)(col >> 8) * RG86_NN + row) * 256 + (col & 255)] =
              rg_f2b(acc[mf][nf][r]);
      }
    }
  }
}

// fp32-A GEMM (R4-proven single-buffer): A staged fp32 via global_load_lds
// (32B-slot XOR swizzle), converted bf16 at fragment load. B bf16.
__global__ __launch_bounds__(256) void rg_gemm2f(
    const float* A, const unsigned short* Bt, const float* bias,
    unsigned short* C, int M, int N, int K, int relu) {
  __shared__ float sA[128 * 64];          // 32 KB fp32 A tile (swizzled)
  __shared__ unsigned short sB[64 * 64];  // 8 KB bf16 B tile (swizzled)
  int tid = threadIdx.x;
  int wv = tid >> 6, lane = tid & 63;
  int nwg = gridDim.x;
  int q = nwg >> 3, rres = nwg & 7;
  int xcd = blockIdx.x & 7, jj = blockIdx.x >> 3;
  int wg = (xcd < rres ? xcd * (q + 1) : rres * (q + 1) + (xcd - rres) * q) + jj;
  int ntiles = N >> 6;
  int mt = wg / ntiles, nt = wg - mt * ntiles;
  int m0 = mt * 128, n0 = nt * 64;
  int frow = lane & 15, fhi = lane >> 4;
  rg_fv4 acc[2][4] = {};
  for (int k0 = 0; k0 < K; k0 += 64) {
#pragma unroll
    for (int i = 0; i < 2; i++) {
      int idx = i * 256 + tid;
      int r = idx >> 3, s = idx & 7;
      const unsigned short* gp = Bt + (size_t)(n0 + r) * K + k0 + ((s ^ (r & 7)) << 3);
      rg_gl16(gp, (char*)sB + (size_t)(i * 256 + wv * 64) * 16);
    }
#pragma unroll
    for (int i = 0; i < 8; i++) {
      int idx = i * 256 + tid;
      int r = idx >> 4, hs = idx & 15;
      int gr = m0 + r;
      if (gr >= M) gr = M - 1;
      const float* gp = A + (size_t)gr * K + k0 +
                        ((((hs >> 1) ^ (r & 7)) << 3) + ((hs & 1) << 2));
      rg_gl16(gp, (char*)sA + (size_t)(i * 256 + wv * 64) * 16);
    }
    __syncthreads();
#pragma unroll
    for (int ks = 0; ks < 2; ks++) {
      rg_bv8 af[2], bf[4];
#pragma unroll
      for (int mf = 0; mf < 2; mf++) {
        int r = wv * 32 + mf * 16 + frow;
        int sp = (ks * 4 + fhi) ^ (r & 7);
        const float* ap = sA + r * 64 + sp * 8;
        float4 f0 = *(const float4*)ap;
        float4 f1 = *(const float4*)(ap + 4);
        rg_sv8 av;
        av[0] = (short)rg_f2b(f0.x); av[1] = (short)rg_f2b(f0.y);
        av[2] = (short)rg_f2b(f0.z); av[3] = (short)rg_f2b(f0.w);
        av[4] = (short)rg_f2b(f1.x); av[5] = (short)rg_f2b(f1.y);
        av[6] = (short)rg_f2b(f1.z); av[7] = (short)rg_f2b(f1.w);
        af[mf] = *(rg_bv8*)&av;
      }
#pragma unroll
      for (int nf = 0; nf < 4; nf++) {
        int r = nf * 16 + frow;
        int slot = (ks * 4 + fhi) ^ (r & 7);
        bf[nf] = *(const rg_bv8*)((const char*)sB + r * 128 + slot * 16);
      }
#pragma unroll
      for (int mf = 0; mf < 2; mf++)
#pragma unroll
        for (int nf = 0; nf < 4; nf++)
          acc[mf][nf] = __builtin_amdgcn_mfma_f32_16x16x32_bf16(af[mf], bf[nf],
                                                                acc[mf][nf], 0, 0, 0);
    }
    __syncthreads();
  }
#pragma unroll
  for (int mf = 0; mf < 2; mf++) {
#pragma unroll
    for (int nf = 0; nf < 4; nf++) {
      int col = n0 + nf * 16 + frow;
      float bv = bias ? bias[col] : 0.f;
#pragma unroll
      for (int r = 0; r < 4; r++) {
        int row = m0 + wv * 32 + mf * 16 + fhi * 4 + r;
        if (row < M) {
          float v = acc[mf][nf][r] + bv;
          if (relu && v < 0.f) v = 0.f;
          C[(size_t)row * N + col] = rg_f2b(v);
        }
      }
    }
  }
}

__global__ void rg_hist(const int* d, int* counts) {
  int e = blockIdx.x * 256 + threadIdx.x;
  if (e < RG86_NE) atomicAdd(&counts[d[e]], 1);
}

// ---- multi-block exclusive scan of counts[n] -> rowptr/cursor ----
__global__ void rg_scan1(const int* counts, int* tmp, int* bsum, int n) {
  int b = blockIdx.x, t = threadIdx.x;
  int base = b * 1024 + t * 4;
  int v0 = 0, v1 = 0, v2 = 0, v3 = 0;
  if (base + 3 < n) {
    int4 v = *(const int4*)(counts + base);
    v0 = v.x; v1 = v.y; v2 = v.z; v3 = v.w;
  } else {
    if (base + 0 < n) v0 = counts[base + 0];
    if (base + 1 < n) v1 = counts[base + 1];
    if (base + 2 < n) v2 = counts[base + 2];
    if (base + 3 < n) v3 = counts[base + 3];
  }
  int tsum = v0 + v1 + v2 + v3;
  int lane = t & 63, wave = t >> 6;
  int s = tsum;
  for (int off = 1; off < 64; off <<= 1) {
    int u = __shfl_up(s, off);
    if (lane >= off) s += u;
  }
  __shared__ int wsum[4];
  if (lane == 63) wsum[wave] = s;
  __syncthreads();
  int woff = 0;
  for (int w = 0; w < wave; w++) woff += wsum[w];
  int excl = woff + s - tsum;
  int e0 = excl, e1 = e0 + v0, e2 = e1 + v1, e3 = e2 + v2;
  if (base + 3 < n) {
    *(int4*)(tmp + base) = make_int4(e0, e1, e2, e3);
  } else {
    if (base + 0 < n) tmp[base + 0] = e0;
    if (base + 1 < n) tmp[base + 1] = e1;
    if (base + 2 < n) tmp[base + 2] = e2;
    if (base + 3 < n) tmp[base + 3] = e3;
  }
  if (t == 255) bsum[b] = woff + s;
}

__global__ void rg_scan2(int* bsum, int* rowptr, int nb, int n) {
  int lane = threadIdx.x;
  int v = (lane < nb) ? bsum[lane] : 0;
  int s = v;
  for (int off = 1; off < 64; off <<= 1) {
    int u = __shfl_up(s, off);
    if (lane >= off) s += u;
  }
  if (lane < nb) bsum[lane] = s - v;
  if (lane == 63) rowptr[n] = s;
}

__global__ void rg_scan3(const int* bsum, int* rowptr, int* cursor, int n) {
  int b = blockIdx.x, t = threadIdx.x;
  int base = b * 1024 + t * 4;
  int off = bsum[b];
  if (base + 3 < n) {
    int4 v = *(const int4*)(cursor + base);
    int4 o = make_int4(v.x + off, v.y + off, v.z + off, v.w + off);
    *(int4*)(rowptr + base) = o;
    *(int4*)(cursor + base) = o;
  } else {
    for (int j = 0; j < 4; j++)
      if (base + j < n) {
        int o = cursor[base + j] + off;
        rowptr[base + j] = o;
        cursor[base + j] = o;
      }
  }
}

__global__ void rg_scatter(const int* d, int* cursor, int* perm) {
  int e = blockIdx.x * 256 + threadIdx.x;
  if (e < RG86_NE) perm[atomicAdd(&cursor[d[e]], 1)] = e;
}

// edge-parallel over CSR-permuted order: leaky-relu logit + fused (rel,src) index
__global__ void rg_edge(const int* perm, const int* src, const int* dst,
                        const int* et, const float* qd, const float* kd,
                        float* alphap, int* srcrel) {
  int i = blockIdx.x * 256 + threadIdx.x;
  if (i >= RG86_NE) return;
  int e = perm[i];
  int t = et[e], sv = src[e], dv = dst[e];
  float al = qd[t * RG86_NN + dv] + kd[t * RG86_NN + sv];
  al = al > 0.f ? al : 0.2f * al;
  alphap[i] = al;
  srcrel[i] = t * RG86_NN + sv;
}

// wave per node: lane-parallel segment softmax over contiguous alphap,
// then LDS-broadcast weighted row gather. out bf16.
__global__ void rg_agg(const int* rowptr, const float* alphap, const int* srcrel,
                       const unsigned short* xw, const float* bias,
                       unsigned short* out) {
  __shared__ float sw[4][64];
  __shared__ int ssrc[4][64];
  int lane = threadIdx.x & 63;
  int wv = threadIdx.x >> 6;
  int node = blockIdx.x * 4 + wv;
  if (node >= RG86_NN) return;
  int s0 = rowptr[node], s1 = rowptr[node + 1];
  int c0 = lane * 4;
  float a0 = 0.f, a1 = 0.f, a2 = 0.f, a3 = 0.f;
  if (s1 > s0) {
    float m = -1e30f;
    for (int bs = s0; bs < s1; bs += 64) {
      int i = bs + lane;
      float al = (i < s1) ? alphap[i] : -1e30f;
      m = fmaxf(m, al);
    }
    for (int o = 32; o >= 1; o >>= 1) m = fmaxf(m, __shfl_xor(m, o));
    float den = 0.f;
    for (int bs = s0; bs < s1; bs += 64) {
      int i = bs + lane;
      if (i < s1) den += __expf(alphap[i] - m);
    }
    for (int o = 32; o >= 1; o >>= 1) den += __shfl_xor(den, o);
    float inv = 1.f / (den + 1e-16f);
    for (int bs = s0; bs < s1; bs += 64) {
      int i = bs + lane;
      int nch = s1 - bs; if (nch > 64) nch = 64;
      float w = 0.f; int sr = 0;
      if (i < s1) { w = __expf(alphap[i] - m) * inv; sr = srcrel[i]; }
      sw[wv][lane] = w;
      ssrc[wv][lane] = sr;
#pragma unroll 4
      for (int j = 0; j < nch; j++) {
        float wj = sw[wv][j];
        ushort4 v = *(const ushort4*)(xw + (size_t)ssrc[wv][j] * RG86_HID + c0);
        a0 += wj * rg_b2f(v.x);
        a1 += wj * rg_b2f(v.y);
        a2 += wj * rg_b2f(v.z);
        a3 += wj * rg_b2f(v.w);
      }
    }
  }
  unsigned short* op = out + (size_t)node * RG86_HID + c0;
  op[0] = rg_f2b(a0 + bias[c0 + 0]);
  op[1] = rg_f2b(a1 + bias[c0 + 1]);
  op[2] = rg_f2b(a2 + bias[c0 + 2]);
  op[3] = rg_f2b(a3 + bias[c0 + 3]);
}

__global__ void rg_cls(const unsigned short* h4, const float* wc, const float* bc,
                       float* out) {
  int n = blockIdx.x * 256 + threadIdx.x;
  if (n >= RG86_NN) return;
  float a0 = bc[0], a1 = bc[1];
  const unsigned short* hr = h4 + (size_t)n * RG86_OUT;
  for (int j = 0; j < RG86_OUT; j++) {
    float h = rg_b2f(hr[j]);
    a0 += h * wc[j * 2 + 0];
    a1 += h * wc[j * 2 + 1];
  }
  out[n * 2 + 0] = a0;
  out[n * 2 + 1] = a1;
}

extern "C" void kernel_launch(void* const* d_in, const int* in_sizes, int n_in,
                              void* d_out, int out_size, void* d_ws, size_t ws_size,
                              hipStream_t stream) {
  (void)in_sizes; (void)n_in; (void)out_size;
  const float* x = (const float*)d_in[0];
  const int* ei = (const int*)d_in[1];
  const int* etp = (const int*)d_in[2];
  const float* w_in = (const float*)d_in[3];
  const float* b_in = (const float*)d_in[4];
  const float* c1w = (const float*)d_in[5];
  const float* c1q = (const float*)d_in[6];
  const float* c1k = (const float*)d_in[7];
  const float* c1b = (const float*)d_in[8];
  const float* c2w = (const float*)d_in[9];
  const float* c2q = (const float*)d_in[10];
  const float* c2k = (const float*)d_in[11];
  const float* c2b = (const float*)d_in[12];
  const float* w_out = (const float*)d_in[13];
  const float* b_out = (const float*)d_in[14];
  const float* w_cls = (const float*)d_in[15];
  const float* b_cls = (const float*)d_in[16];
  const int* esrc = ei;
  const int* edst = ei + RG86_NE;

  char* base = (char*)d_ws;
  size_t off = 0;
  unsigned short* xw = (unsigned short*)(base + off);
  off += (size_t)RG86_NR * RG86_NN * RG86_HID * 2;  // 76.8 MB
  unsigned short* h1b = (unsigned short*)(base + off); off += (size_t)RG86_NN * RG86_HID * 2;
  unsigned short* h2b = (unsigned short*)(base + off); off += (size_t)RG86_NN * RG86_HID * 2;
  unsigned short* h4b = (unsigned short*)(base + off); off += (size_t)RG86_NN * RG86_OUT * 2;
  unsigned short* w_inT = (unsigned short*)(base + off); off += (size_t)RG86_DIN * RG86_HID * 2;
  unsigned short* c1wT = (unsigned short*)(base + off); off += (size_t)RG86_NR * RG86_HID * RG86_HID * 2;
  unsigned short* c2wT = (unsigned short*)(base + off); off += (size_t)RG86_NR * RG86_HID * RG86_HID * 2;
  unsigned short* w_outT = (unsigned short*)(base + off); off += (size_t)RG86_HID * RG86_OUT * 2;
  float* qd = (float*)(base + off); off += (size_t)RG86_NR * RG86_NN * 4;
  float* kd = (float*)(base + off); off += (size_t)RG86_NR * RG86_NN * 4;
  float* wq1 = (float*)(base + off); off += (size_t)RG86_NR * RG86_HID * 4;
  float* wk1 = (float*)(base + off); off += (size_t)RG86_NR * RG86_HID * 4;
  float* wq2 = (float*)(base + off); off += (size_t)RG86_NR * RG86_HID * 4;
  float* wk2 = (float*)(base + off); off += (size_t)RG86_NR * RG86_HID * 4;
  int* counts = (int*)(base + off); off += (size_t)RG86_NN * 4;
  int* rowptr = (int*)(base + off); off += (size_t)(RG86_NN + 4) * 4;
  int* cursor = (int*)(base + off); off += (size_t)RG86_NN * 4;
  int* perm = (int*)(base + off); off += (size_t)RG86_NE * 4;
  int* bsum = (int*)(base + off); off += (size_t)64 * 4;
  float* alphap = (float*)(base + off); off += (size_t)RG86_NE * 4;
  int* srcrel = (int*)(base + off); off += (size_t)RG86_NE * 4;
  if (off > ws_size) return;

  int mt128 = (RG86_NN + 127) / 128;       // 391 m-tiles
  int nsb = (RG86_NN + 1023) / 1024;       // 49 scan blocks (<= 64)

  // weight preps
  rg_castT<<<(RG86_DIN * RG86_HID + 255) / 256, 256, 0, stream>>>(
      w_in, w_inT, RG86_DIN, RG86_HID);
  rg_castT3<<<(RG86_NR * RG86_HID * RG86_HID + 255) / 256, 256, 0, stream>>>(c1w, c1wT);
  rg_castT3<<<(RG86_NR * RG86_HID * RG86_HID + 255) / 256, 256, 0, stream>>>(c2w, c2wT);
  rg_castT<<<(RG86_HID * RG86_OUT + 255) / 256, 256, 0, stream>>>(
      w_out, w_outT, RG86_HID, RG86_OUT);
  rg_wqk<<<(RG86_NR * RG86_HID + 3) / 4, 256, 0, stream>>>(c1w, c1q, c1k, wq1, wk1);
  rg_wqk<<<(RG86_NR * RG86_HID + 3) / 4, 256, 0, stream>>>(c2w, c2q, c2k, wq2, wk2);

  // h1 = relu(x @ w_in + b_in), fp32 A staged async (R4 single-buffer)
  rg_gemm2f<<<mt128 * 4, 256, 0, stream>>>(x, w_inT, b_in, h1b,
                                           RG86_NN, RG86_HID, RG86_DIN, 1);

  // CSR by dst (multi-block scan)
  hipMemsetAsync(counts, 0, (size_t)RG86_NN * 4, stream);
  rg_hist<<<(RG86_NE + 255) / 256, 256, 0, stream>>>(edst, counts);
  rg_scan1<<<nsb, 256, 0, stream>>>(counts, cursor, bsum, RG86_NN);
  rg_scan2<<<1, 64, 0, stream>>>(bsum, rowptr, nsb, RG86_NN);
  rg_scan3<<<nsb, 256, 0, stream>>>(bsum, rowptr, cursor, RG86_NN);
  rg_scatter<<<(RG86_NE + 255) / 256, 256, 0, stream>>>(edst, cursor, perm);

  // conv1: fused 3-relation wide GEMM (N=768 = 6 x 128-tiles, split output)
  rg_gemm2w<<<mt128 * 6, 256, 0, stream>>>(h1b, c1wT, xw,
                                           RG86_NN, RG86_NR * RG86_HID, RG86_HID);
  rg_qk2<<<(RG86_NN + 3) / 4, 256, 0, stream>>>(h1b, wq1, wk1, qd, kd);
  rg_edge<<<(RG86_NE + 255) / 256, 256, 0, stream>>>(perm, esrc, edst, etp, qd, kd,
                                                     alphap, srcrel);
  rg_agg<<<(RG86_NN + 3) / 4, 256, 0, stream>>>(rowptr, alphap, srcrel,
                                                xw, c1b, h2b);

  // conv2
  rg_gemm2w<<<mt128 * 6, 256, 0, stream>>>(h2b, c2wT, xw,
                                           RG86_NN, RG86_NR * RG86_HID, RG86_HID);
  rg_qk2<<<(RG86_NN + 3) / 4, 256, 0, stream>>>(h2b, wq2, wk2, qd, kd);
  rg_edge<<<(RG86_NE + 255) / 256, 256, 0, stream>>>(perm, esrc, edst, etp, qd, kd,
                                                     alphap, srcrel);
  rg_agg<<<(RG86_NN + 3) / 4, 256, 0, stream>>>(rowptr, alphap, srcrel,
                                                xw, c2b, h1b);

  // h4 = relu(h @ w_out + b_out)
  rg_gemm2<<<mt128, 256, 0, stream>>>(h1b, w_outT, b_out, h4b,
                                      RG86_NN, RG86_OUT, RG86_HID, 1, 0);

  // logits
  rg_cls<<<(RG86_NN + 255) / 256, 256, 0, stream>>>(h4b, w_cls, b_cls, (float*)d_out);
}

// Round 9
// 569.829 us; speedup vs baseline: 1.1300x; 1.0026x over previous
//
#include <hip/hip_runtime.h>
#include <hip/hip_bf16.h>

#define RG86_NN 50000
#define RG86_NE 320000
#define RG86_NR 3
#define RG86_DIN 768
#define RG86_HID 256
#define RG86_OUT 64

typedef __bf16 rg_bv8 __attribute__((ext_vector_type(8)));
typedef short rg_sv8 __attribute__((ext_vector_type(8)));
typedef float rg_fv4 __attribute__((ext_vector_type(4)));
typedef unsigned int rg_u32;

static __device__ float rg_b2f(unsigned short u) {
  return __uint_as_float(((unsigned int)u) << 16);
}
static __device__ unsigned short rg_f2b(float f) {
  unsigned int u = __float_as_uint(f);
  u += 0x7FFFu + ((u >> 16) & 1u);
  return (unsigned short)(u >> 16);
}

// async global->LDS, 16B per lane. lds arg must be the WAVE-uniform base;
// HW scatters lane l to base + l*16.
static __device__ __forceinline__ void rg_gl16(const void* g, void* lds_wave_base) {
  __builtin_amdgcn_global_load_lds(
      (const __attribute__((address_space(1))) rg_u32*)(unsigned long long)(uintptr_t)g,
      (__attribute__((address_space(3))) rg_u32*)(unsigned int)(uintptr_t)lds_wave_base,
      16, 0, 0);
}

__global__ void RGATModel_86371792322702_kernel() {}

// fp32 [rows][cols] -> bf16 [cols][rows]
__global__ void rg_castT(const float* in, unsigned short* out, int rows, int cols) {
  int i = blockIdx.x * 256 + threadIdx.x;
  if (i < rows * cols) {
    int r = i / cols, c = i % cols;
    out[(size_t)c * rows + r] = rg_f2b(in[i]);
  }
}

// 3-relation [256][256] transpose cast (one launch for a whole conv weight)
__global__ void rg_castT3(const float* in, unsigned short* out) {
  int i = blockIdx.x * 256 + threadIdx.x;
  if (i < RG86_NR * RG86_HID * RG86_HID) {
    int r = i >> 16, j = i & 65535;
    int row = j >> 8, col = j & 255;
    out[(r << 16) + (col << 8) + row] = rg_f2b(in[i]);
  }
}

// wq[r][c] = sum_o W[r][c][o]*q[o]; wk likewise. One wave per (r,c) row.
__global__ void rg_wqk(const float* W, const float* q, const float* k,
                       float* wq, float* wk) {
  int lane = threadIdx.x & 63;
  int p = blockIdx.x * 4 + (threadIdx.x >> 6);
  if (p >= RG86_NR * RG86_HID) return;
  const float* wr = W + (size_t)p * RG86_HID;
  float qv = 0.f, kv = 0.f;
  for (int j = lane; j < RG86_HID; j += 64) {
    float w = wr[j];
    qv += w * q[j];
    kv += w * k[j];
  }
  for (int o = 32; o >= 1; o >>= 1) { qv += __shfl_xor(qv, o); kv += __shfl_xor(kv, o); }
  if (lane == 0) { wq[p] = qv; wk[p] = kv; }
}

// qd[r][n] = h[n] . wq[r]  (identity: (h@W)q == h@(Wq)). Wave per node, 6 dots.
__global__ void rg_qk2(const unsigned short* h, const float* wq, const float* wk,
                       float* qd, float* kd) {
  int lane = threadIdx.x & 63;
  int n = blockIdx.x * 4 + (threadIdx.x >> 6);
  if (n >= RG86_NN) return;
  ushort4 hv = *(const ushort4*)(h + (size_t)n * RG86_HID + lane * 4);
  float h0 = rg_b2f(hv.x), h1 = rg_b2f(hv.y), h2 = rg_b2f(hv.z), h3 = rg_b2f(hv.w);
  float acc[6];
#pragma unroll
  for (int r = 0; r < RG86_NR; r++) {
    const float* wqr = wq + r * RG86_HID + lane * 4;
    const float* wkr = wk + r * RG86_HID + lane * 4;
    acc[r] = h0 * wqr[0] + h1 * wqr[1] + h2 * wqr[2] + h3 * wqr[3];
    acc[3 + r] = h0 * wkr[0] + h1 * wkr[1] + h2 * wkr[2] + h3 * wkr[3];
  }
#pragma unroll
  for (int j = 0; j < 6; j++)
    for (int o = 32; o >= 1; o >>= 1) acc[j] += __shfl_xor(acc[j], o);
  if (lane == 0) {
#pragma unroll
    for (int r = 0; r < RG86_NR; r++) {
      qd[r * RG86_NN + n] = acc[r];
      kd[r * RG86_NN + n] = acc[3 + r];
    }
  }
}

// Wide MFMA GEMM: 128x128 tile, BK=64, single-buffer 1-phase. 32 MFMA per
// K-step per wave -> more compute per barrier drain. Used for conv GEMMs
// (N=768, split output into xw[r][node][HID]).
__global__ __launch_bounds__(256) void rg_gemm2w(
    const unsigned short* A, const unsigned short* Bt,
    unsigned short* C, int M, int N, int K) {
  __shared__ unsigned short sA[128 * 64];
  __shared__ unsigned short sB[128 * 64];
  int tid = threadIdx.x;
  int wv = tid >> 6, lane = tid & 63;
  int nwg = gridDim.x;
  int q = nwg >> 3, rres = nwg & 7;
  int xcd = blockIdx.x & 7, jj = blockIdx.x >> 3;
  int wg = (xcd < rres ? xcd * (q + 1) : rres * (q + 1) + (xcd - rres) * q) + jj;
  int ntiles = N >> 7;
  int mt = wg / ntiles, nt = wg - mt * ntiles;
  int m0 = mt * 128, n0 = nt * 128;
  int frow = lane & 15, fhi = lane >> 4;
  rg_fv4 acc[2][8] = {};
  for (int k0 = 0; k0 < K; k0 += 64) {
#pragma unroll
    for (int i = 0; i < 4; i++) {
      int idx = i * 256 + tid;
      int r = idx >> 3, s = idx & 7;
      int gr = m0 + r;
      if (gr >= M) gr = M - 1;
      const unsigned short* gp = A + (size_t)gr * K + k0 + ((s ^ (r & 7)) << 3);
      rg_gl16(gp, (char*)sA + (size_t)(i * 256 + wv * 64) * 16);
    }
#pragma unroll
    for (int i = 0; i < 4; i++) {
      int idx = i * 256 + tid;
      int r = idx >> 3, s = idx & 7;
      const unsigned short* gp = Bt + (size_t)(n0 + r) * K + k0 + ((s ^ (r & 7)) << 3);
      rg_gl16(gp, (char*)sB + (size_t)(i * 256 + wv * 64) * 16);
    }
    __syncthreads();
#pragma unroll
    for (int ks = 0; ks < 2; ks++) {
      rg_bv8 af[2], bf[8];
#pragma unroll
      for (int mf = 0; mf < 2; mf++) {
        int r = wv * 32 + mf * 16 + frow;
        int slot = (ks * 4 + fhi) ^ (r & 7);
        af[mf] = *(const rg_bv8*)((const char*)sA + r * 128 + slot * 16);
      }
#pragma unroll
      for (int nf = 0; nf < 8; nf++) {
        int r = nf * 16 + frow;
        int slot = (ks * 4 + fhi) ^ (r & 7);
        bf[nf] = *(const rg_bv8*)((const char*)sB + r * 128 + slot * 16);
      }
#pragma unroll
      for (int mf = 0; mf < 2; mf++)
#pragma unroll
        for (int nf = 0; nf < 8; nf++)
          acc[mf][nf] = __builtin_amdgcn_mfma_f32_16x16x32_bf16(af[mf], bf[nf],
                                                                acc[mf][nf], 0, 0, 0);
    }
    __syncthreads();
  }
  // split epilogue: col -> relation (col>>8), inner col&255
#pragma unroll
  for (int mf = 0; mf < 2; mf++) {
#pragma unroll
    for (int nf = 0; nf < 8; nf++) {
      int col = n0 + nf * 16 + frow;
#pragma unroll
      for (int r = 0; r < 4; r++) {
        int row = m0 + wv * 32 + mf * 16 + fhi * 4 + r;
        if (row < M)
          C[((size_t)(col >> 8) * RG86_NN + row) * 256 + (col & 255)] =
              rg_f2b(acc[mf][nf][r]);
      }
    }
  }
}

// fp32-A GEMM, wide 128x128 tile: A staged fp32 via global_load_lds (32B-slot
// XOR swizzle, 32 KB), B bf16 (16 KB). 32 MFMA per K-step per wave.
__global__ __launch_bounds__(256) void rg_gemm2f(
    const float* A, const unsigned short* Bt, const float* bias,
    unsigned short* C, int M, int N, int K, int relu) {
  __shared__ float sA[128 * 64];           // 32 KB fp32 A tile (swizzled)
  __shared__ unsigned short sB[128 * 64];  // 16 KB bf16 B tile (swizzled)
  int tid = threadIdx.x;
  int wv = tid >> 6, lane = tid & 63;
  int nwg = gridDim.x;
  int q = nwg >> 3, rres = nwg & 7;
  int xcd = blockIdx.x & 7, jj = blockIdx.x >> 3;
  int wg = (xcd < rres ? xcd * (q + 1) : rres * (q + 1) + (xcd - rres) * q) + jj;
  int ntiles = N >> 7;
  int mt = wg / ntiles, nt = wg - mt * ntiles;
  int m0 = mt * 128, n0 = nt * 128;
  int frow = lane & 15, fhi = lane >> 4;
  rg_fv4 acc[2][8] = {};
  for (int k0 = 0; k0 < K; k0 += 64) {
#pragma unroll
    for (int i = 0; i < 4; i++) {
      int idx = i * 256 + tid;
      int r = idx >> 3, s = idx & 7;
      const unsigned short* gp = Bt + (size_t)(n0 + r) * K + k0 + ((s ^ (r & 7)) << 3);
      rg_gl16(gp, (char*)sB + (size_t)(i * 256 + wv * 64) * 16);
    }
#pragma unroll
    for (int i = 0; i < 8; i++) {
      int idx = i * 256 + tid;
      int r = idx >> 4, hs = idx & 15;
      int gr = m0 + r;
      if (gr >= M) gr = M - 1;
      const float* gp = A + (size_t)gr * K + k0 +
                        ((((hs >> 1) ^ (r & 7)) << 3) + ((hs & 1) << 2));
      rg_gl16(gp, (char*)sA + (size_t)(i * 256 + wv * 64) * 16);
    }
    __syncthreads();
#pragma unroll
    for (int ks = 0; ks < 2; ks++) {
      rg_bv8 af[2], bf[8];
#pragma unroll
      for (int mf = 0; mf < 2; mf++) {
        int r = wv * 32 + mf * 16 + frow;
        int sp = (ks * 4 + fhi) ^ (r & 7);
        const float* ap = sA + r * 64 + sp * 8;
        float4 f0 = *(const float4*)ap;
        float4 f1 = *(const float4*)(ap + 4);
        rg_sv8 av;
        av[0] = (short)rg_f2b(f0.x); av[1] = (short)rg_f2b(f0.y);
        av[2] = (short)rg_f2b(f0.z); av[3] = (short)rg_f2b(f0.w);
        av[4] = (short)rg_f2b(f1.x); av[5] = (short)rg_f2b(f1.y);
        av[6] = (short)rg_f2b(f1.z); av[7] = (short)rg_f2b(f1.w);
        af[mf] = *(rg_bv8*)&av;
      }
#pragma unroll
      for (int nf = 0; nf < 8; nf++) {
        int r = nf * 16 + frow;
        int slot = (ks * 4 + fhi) ^ (r & 7);
        bf[nf] = *(const rg_bv8*)((const char*)sB + r * 128 + slot * 16);
      }
#pragma unroll
      for (int mf = 0; mf < 2; mf++)
#pragma unroll
        for (int nf = 0; nf < 8; nf++)
          acc[mf][nf] = __builtin_amdgcn_mfma_f32_16x16x32_bf16(af[mf], bf[nf],
                                                                acc[mf][nf], 0, 0, 0);
    }
    __syncthreads();
  }
#pragma unroll
  for (int mf = 0; mf < 2; mf++) {
#pragma unroll
    for (int nf = 0; nf < 8; nf++) {
      int col = n0 + nf * 16 + frow;
      float bv = bias ? bias[col] : 0.f;
#pragma unroll
      for (int r = 0; r < 4; r++) {
        int row = m0 + wv * 32 + mf * 16 + fhi * 4 + r;
        if (row < M) {
          float v = acc[mf][nf][r] + bv;
          if (relu && v < 0.f) v = 0.f;
          C[(size_t)row * N + col] = rg_f2b(v);
        }
      }
    }
  }
}

// Fused h4+cls GEMM: 128x64 tile over A[M][256] x w_outT[64][256]^T; epilogue
// applies bias+relu in-register, dots with w_cls (64x2), 16-lane shfl reduce,
// writes fp32 logits. h4 never materialized.
__global__ __launch_bounds__(256) void rg_gemm2c(
    const unsigned short* A, const unsigned short* Bt, const float* bias,
    const float* wc, const float* bc, float* out, int M, int K) {
  __shared__ unsigned short sA[128 * 64];
  __shared__ unsigned short sB[64 * 64];
  int tid = threadIdx.x;
  int wv = tid >> 6, lane = tid & 63;
  int mt = blockIdx.x;
  int m0 = mt * 128;
  int frow = lane & 15, fhi = lane >> 4;
  rg_fv4 acc[2][4] = {};
  for (int k0 = 0; k0 < K; k0 += 64) {
#pragma unroll
    for (int i = 0; i < 4; i++) {
      int idx = i * 256 + tid;
      int r = idx >> 3, s = idx & 7;
      int gr = m0 + r;
      if (gr >= M) gr = M - 1;
      const unsigned short* gp = A + (size_t)gr * K + k0 + ((s ^ (r & 7)) << 3);
      rg_gl16(gp, (char*)sA + (size_t)(i * 256 + wv * 64) * 16);
    }
#pragma unroll
    for (int i = 0; i < 2; i++) {
      int idx = i * 256 + tid;
      int r = idx >> 3, s = idx & 7;
      const unsigned short* gp = Bt + (size_t)r * K + k0 + ((s ^ (r & 7)) << 3);
      rg_gl16(gp, (char*)sB + (size_t)(i * 256 + wv * 64) * 16);
    }
    __syncthreads();
#pragma unroll
    for (int ks = 0; ks < 2; ks++) {
      rg_bv8 af[2], bf[4];
#pragma unroll
      for (int mf = 0; mf < 2; mf++) {
        int r = wv * 32 + mf * 16 + frow;
        int slot = (ks * 4 + fhi) ^ (r & 7);
        af[mf] = *(const rg_bv8*)((const char*)sA + r * 128 + slot * 16);
      }
#pragma unroll
      for (int nf = 0; nf < 4; nf++) {
        int r = nf * 16 + frow;
        int slot = (ks * 4 + fhi) ^ (r & 7);
        bf[nf] = *(const rg_bv8*)((const char*)sB + r * 128 + slot * 16);
      }
#pragma unroll
      for (int mf = 0; mf < 2; mf++)
#pragma unroll
        for (int nf = 0; nf < 4; nf++)
          acc[mf][nf] = __builtin_amdgcn_mfma_f32_16x16x32_bf16(af[mf], bf[nf],
                                                                acc[mf][nf], 0, 0, 0);
    }
    __syncthreads();
  }
  float bc0 = bc[0], bc1 = bc[1];
#pragma unroll
  for (int mf = 0; mf < 2; mf++) {
#pragma unroll
    for (int r = 0; r < 4; r++) {
      float p0 = 0.f, p1 = 0.f;
#pragma unroll
      for (int nf = 0; nf < 4; nf++) {
        int col = nf * 16 + frow;
        float v = acc[mf][nf][r] + bias[col];
        if (v < 0.f) v = 0.f;
        p0 += v * wc[col * 2 + 0];
        p1 += v * wc[col * 2 + 1];
      }
#pragma unroll
      for (int o = 1; o < 16; o <<= 1) {
        p0 += __shfl_xor(p0, o);
        p1 += __shfl_xor(p1, o);
      }
      int row = m0 + wv * 32 + mf * 16 + fhi * 4 + r;
      if (frow == 0 && row < M) {
        out[row * 2 + 0] = p0 + bc0;
        out[row * 2 + 1] = p1 + bc1;
      }
    }
  }
}

__global__ void rg_hist(const int* d, int* counts) {
  int e = blockIdx.x * 256 + threadIdx.x;
  if (e < RG86_NE) atomicAdd(&counts[d[e]], 1);
}

// ---- multi-block exclusive scan of counts[n] -> rowptr/cursor ----
__global__ void rg_scan1(const int* counts, int* tmp, int* bsum, int n) {
  int b = blockIdx.x, t = threadIdx.x;
  int base = b * 1024 + t * 4;
  int v0 = 0, v1 = 0, v2 = 0, v3 = 0;
  if (base + 3 < n) {
    int4 v = *(const int4*)(counts + base);
    v0 = v.x; v1 = v.y; v2 = v.z; v3 = v.w;
  } else {
    if (base + 0 < n) v0 = counts[base + 0];
    if (base + 1 < n) v1 = counts[base + 1];
    if (base + 2 < n) v2 = counts[base + 2];
    if (base + 3 < n) v3 = counts[base + 3];
  }
  int tsum = v0 + v1 + v2 + v3;
  int lane = t & 63, wave = t >> 6;
  int s = tsum;
  for (int off = 1; off < 64; off <<= 1) {
    int u = __shfl_up(s, off);
    if (lane >= off) s += u;
  }
  __shared__ int wsum[4];
  if (lane == 63) wsum[wave] = s;
  __syncthreads();
  int woff = 0;
  for (int w = 0; w < wave; w++) woff += wsum[w];
  int excl = woff + s - tsum;
  int e0 = excl, e1 = e0 + v0, e2 = e1 + v1, e3 = e2 + v2;
  if (base + 3 < n) {
    *(int4*)(tmp + base) = make_int4(e0, e1, e2, e3);
  } else {
    if (base + 0 < n) tmp[base + 0] = e0;
    if (base + 1 < n) tmp[base + 1] = e1;
    if (base + 2 < n) tmp[base + 2] = e2;
    if (base + 3 < n) tmp[base + 3] = e3;
  }
  if (t == 255) bsum[b] = woff + s;
}

__global__ void rg_scan2(int* bsum, int* rowptr, int nb, int n) {
  int lane = threadIdx.x;
  int v = (lane < nb) ? bsum[lane] : 0;
  int s = v;
  for (int off = 1; off < 64; off <<= 1) {
    int u = __shfl_up(s, off);
    if (lane >= off) s += u;
  }
  if (lane < nb) bsum[lane] = s - v;
  if (lane == 63) rowptr[n] = s;
}

__global__ void rg_scan3(const int* bsum, int* rowptr, int* cursor, int n) {
  int b = blockIdx.x, t = threadIdx.x;
  int base = b * 1024 + t * 4;
  int off = bsum[b];
  if (base + 3 < n) {
    int4 v = *(const int4*)(cursor + base);
    int4 o = make_int4(v.x + off, v.y + off, v.z + off, v.w + off);
    *(int4*)(rowptr + base) = o;
    *(int4*)(cursor + base) = o;
  } else {
    for (int j = 0; j < 4; j++)
      if (base + j < n) {
        int o = cursor[base + j] + off;
        rowptr[base + j] = o;
        cursor[base + j] = o;
      }
  }
}

__global__ void rg_scatter(const int* d, int* cursor, int* perm) {
  int e = blockIdx.x * 256 + threadIdx.x;
  if (e < RG86_NE) perm[atomicAdd(&cursor[d[e]], 1)] = e;
}

// edge-parallel over CSR-permuted order: leaky-relu logit + fused (rel,src) index
__global__ void rg_edge(const int* perm, const int* src, const int* dst,
                        const int* et, const float* qd, const float* kd,
                        float* alphap, int* srcrel) {
  int i = blockIdx.x * 256 + threadIdx.x;
  if (i >= RG86_NE) return;
  int e = perm[i];
  int t = et[e], sv = src[e], dv = dst[e];
  float al = qd[t * RG86_NN + dv] + kd[t * RG86_NN + sv];
  al = al > 0.f ? al : 0.2f * al;
  alphap[i] = al;
  srcrel[i] = t * RG86_NN + sv;
}

// wave per node: lane-parallel segment softmax over contiguous alphap,
// then LDS-broadcast weighted row gather. out bf16.
__global__ void rg_agg(const int* rowptr, const float* alphap, const int* srcrel,
                       const unsigned short* xw, const float* bias,
                       unsigned short* out) {
  __shared__ float sw[4][64];
  __shared__ int ssrc[4][64];
  int lane = threadIdx.x & 63;
  int wv = threadIdx.x >> 6;
  int node = blockIdx.x * 4 + wv;
  if (node >= RG86_NN) return;
  int s0 = rowptr[node], s1 = rowptr[node + 1];
  int c0 = lane * 4;
  float a0 = 0.f, a1 = 0.f, a2 = 0.f, a3 = 0.f;
  if (s1 > s0) {
    float m = -1e30f;
    for (int bs = s0; bs < s1; bs += 64) {
      int i = bs + lane;
      float al = (i < s1) ? alphap[i] : -1e30f;
      m = fmaxf(m, al);
    }
    for (int o = 32; o >= 1; o >>= 1) m = fmaxf(m, __shfl_xor(m, o));
    float den = 0.f;
    for (int bs = s0; bs < s1; bs += 64) {
      int i = bs + lane;
      if (i < s1) den += __expf(alphap[i] - m);
    }
    for (int o = 32; o >= 1; o >>= 1) den += __shfl_xor(den, o);
    float inv = 1.f / (den + 1e-16f);
    for (int bs = s0; bs < s1; bs += 64) {
      int i = bs + lane;
      int nch = s1 - bs; if (nch > 64) nch = 64;
      float w = 0.f; int sr = 0;
      if (i < s1) { w = __expf(alphap[i] - m) * inv; sr = srcrel[i]; }
      sw[wv][lane] = w;
      ssrc[wv][lane] = sr;
#pragma unroll 4
      for (int j = 0; j < nch; j++) {
        float wj = sw[wv][j];
        ushort4 v = *(const ushort4*)(xw + (size_t)ssrc[wv][j] * RG86_HID + c0);
        a0 += wj * rg_b2f(v.x);
        a1 += wj * rg_b2f(v.y);
        a2 += wj * rg_b2f(v.z);
        a3 += wj * rg_b2f(v.w);
      }
    }
  }
  unsigned short* op = out + (size_t)node * RG86_HID + c0;
  op[0] = rg_f2b(a0 + bias[c0 + 0]);
  op[1] = rg_f2b(a1 + bias[c0 + 1]);
  op[2] = rg_f2b(a2 + bias[c0 + 2]);
  op[3] = rg_f2b(a3 + bias[c0 + 3]);
}

extern "C" void kernel_launch(void* const* d_in, const int* in_sizes, int n_in,
                              void* d_out, int out_size, void* d_ws, size_t ws_size,
                              hipStream_t stream) {
  (void)in_sizes; (void)n_in; (void)out_size;
  const float* x = (const float*)d_in[0];
  const int* ei = (const int*)d_in[1];
  const int* etp = (const int*)d_in[2];
  const float* w_in = (const float*)d_in[3];
  const float* b_in = (const float*)d_in[4];
  const float* c1w = (const float*)d_in[5];
  const float* c1q = (const float*)d_in[6];
  const float* c1k = (const float*)d_in[7];
  const float* c1b = (const float*)d_in[8];
  const float* c2w = (const float*)d_in[9];
  const float* c2q = (const float*)d_in[10];
  const float* c2k = (const float*)d_in[11];
  const float* c2b = (const float*)d_in[12];
  const float* w_out = (const float*)d_in[13];
  const float* b_out = (const float*)d_in[14];
  const float* w_cls = (const float*)d_in[15];
  const float* b_cls = (const float*)d_in[16];
  const int* esrc = ei;
  const int* edst = ei + RG86_NE;

  char* base = (char*)d_ws;
  size_t off = 0;
  unsigned short* xw = (unsigned short*)(base + off);
  off += (size_t)RG86_NR * RG86_NN * RG86_HID * 2;  // 76.8 MB
  unsigned short* h1b = (unsigned short*)(base + off); off += (size_t)RG86_NN * RG86_HID * 2;
  unsigned short* h2b = (unsigned short*)(base + off); off += (size_t)RG86_NN * RG86_HID * 2;
  unsigned short* w_inT = (unsigned short*)(base + off); off += (size_t)RG86_DIN * RG86_HID * 2;
  unsigned short* c1wT = (unsigned short*)(base + off); off += (size_t)RG86_NR * RG86_HID * RG86_HID * 2;
  unsigned short* c2wT = (unsigned short*)(base + off); off += (size_t)RG86_NR * RG86_HID * RG86_HID * 2;
  unsigned short* w_outT = (unsigned short*)(base + off); off += (size_t)RG86_HID * RG86_OUT * 2;
  float* qd = (float*)(base + off); off += (size_t)RG86_NR * RG86_NN * 4;
  float* kd = (float*)(base + off); off += (size_t)RG86_NR * RG86_NN * 4;
  float* wq1 = (float*)(base + off); off += (size_t)RG86_NR * RG86_HID * 4;
  float* wk1 = (float*)(base + off); off += (size_t)RG86_NR * RG86_HID * 4;
  float* wq2 = (float*)(base + off); off += (size_t)RG86_NR * RG86_HID * 4;
  float* wk2 = (float*)(base + off); off += (size_t)RG86_NR * RG86_HID * 4;
  int* counts = (int*)(base + off); off += (size_t)RG86_NN * 4;
  int* rowptr = (int*)(base + off); off += (size_t)(RG86_NN + 4) * 4;
  int* cursor = (int*)(base + off); off += (size_t)RG86_NN * 4;
  int* perm = (int*)(base + off); off += (size_t)RG86_NE * 4;
  int* bsum = (int*)(base + off); off += (size_t)64 * 4;
  float* alphap = (float*)(base + off); off += (size_t)RG86_NE * 4;
  int* srcrel = (int*)(base + off); off += (size_t)RG86_NE * 4;
  if (off > ws_size) return;

  int mt128 = (RG86_NN + 127) / 128;       // 391 m-tiles
  int nsb = (RG86_NN + 1023) / 1024;       // 49 scan blocks (<= 64)

  // weight preps
  rg_castT<<<(RG86_DIN * RG86_HID + 255) / 256, 256, 0, stream>>>(
      w_in, w_inT, RG86_DIN, RG86_HID);
  rg_castT3<<<(RG86_NR * RG86_HID * RG86_HID + 255) / 256, 256, 0, stream>>>(c1w, c1wT);
  rg_castT3<<<(RG86_NR * RG86_HID * RG86_HID + 255) / 256, 256, 0, stream>>>(c2w, c2wT);
  rg_castT<<<(RG86_HID * RG86_OUT + 255) / 256, 256, 0, stream>>>(
      w_out, w_outT, RG86_HID, RG86_OUT);
  rg_wqk<<<(RG86_NR * RG86_HID + 3) / 4, 256, 0, stream>>>(c1w, c1q, c1k, wq1, wk1);
  rg_wqk<<<(RG86_NR * RG86_HID + 3) / 4, 256, 0, stream>>>(c2w, c2q, c2k, wq2, wk2);

  // h1 = relu(x @ w_in + b_in), fp32 A staged async, wide 128x128 tile
  rg_gemm2f<<<mt128 * 2, 256, 0, stream>>>(x, w_inT, b_in, h1b,
                                           RG86_NN, RG86_HID, RG86_DIN, 1);

  // CSR by dst (multi-block scan)
  hipMemsetAsync(counts, 0, (size_t)RG86_NN * 4, stream);
  rg_hist<<<(RG86_NE + 255) / 256, 256, 0, stream>>>(edst, counts);
  rg_scan1<<<nsb, 256, 0, stream>>>(counts, cursor, bsum, RG86_NN);
  rg_scan2<<<1, 64, 0, stream>>>(bsum, rowptr, nsb, RG86_NN);
  rg_scan3<<<nsb, 256, 0, stream>>>(bsum, rowptr, cursor, RG86_NN);
  rg_scatter<<<(RG86_NE + 255) / 256, 256, 0, stream>>>(edst, cursor, perm);

  // conv1: fused 3-relation wide GEMM (N=768 = 6 x 128-tiles, split output)
  rg_gemm2w<<<mt128 * 6, 256, 0, stream>>>(h1b, c1wT, xw,
                                           RG86_NN, RG86_NR * RG86_HID, RG86_HID);
  rg_qk2<<<(RG86_NN + 3) / 4, 256, 0, stream>>>(h1b, wq1, wk1, qd, kd);
  rg_edge<<<(RG86_NE + 255) / 256, 256, 0, stream>>>(perm, esrc, edst, etp, qd, kd,
                                                     alphap, srcrel);
  rg_agg<<<(RG86_NN + 3) / 4, 256, 0, stream>>>(rowptr, alphap, srcrel,
                                                xw, c1b, h2b);

  // conv2
  rg_gemm2w<<<mt128 * 6, 256, 0, stream>>>(h2b, c2wT, xw,
                                           RG86_NN, RG86_NR * RG86_HID, RG86_HID);
  rg_qk2<<<(RG86_NN + 3) / 4, 256, 0, stream>>>(h2b, wq2, wk2, qd, kd);
  rg_edge<<<(RG86_NE + 255) / 256, 256, 0, stream>>>(perm, esrc, edst, etp, qd, kd,
                                                     alphap, srcrel);
  rg_agg<<<(RG86_NN + 3) / 4, 256, 0, stream>>>(rowptr, alphap, srcrel,
                                                xw, c2b, h1b);

  // logits = (relu(h @ w_out + b_out)) @ w_cls + b_cls, fused
  rg_gemm2c<<<mt128, 256, 0, stream>>>(h1b, w_outT, b_out, w_cls, b_cls,
                                       (float*)d_out, RG86_NN, RG86_HID);
}